// Round 14
// baseline (189.172 us; speedup 1.0000x reference)
//
#include <hip/hip_runtime.h>
#include <cstdio>
#include <cstdint>

// Problem constants
#define BATCH 8
#define CH    512
#define OC3   1536      // 3*CH
#define NPIX  4096      // 64*64
#define HEADS 8
#define HDIM  64
#define KDEPTH 512
#define SCALE 0.125f    // 64^-0.5
#define GSPLIT 4        // split-K for Gram (1024 n per split)

typedef __bf16 bf16;
typedef __bf16 bf16x4 __attribute__((ext_vector_type(4)));
typedef __bf16 bf16x8 __attribute__((ext_vector_type(8)));
typedef float  f32x4  __attribute__((ext_vector_type(4)));

#define AS1 __attribute__((address_space(1)))
#define AS3 __attribute__((address_space(3)))

// ---------------------------------------------------------------------------
// fp32 -> bf16 flat convert (weights)
// ---------------------------------------------------------------------------
__global__ __launch_bounds__(256) void convert_bf16_kernel(
    const float* __restrict__ in, bf16* __restrict__ out, int n)
{
    const int i = blockIdx.x * 256 + threadIdx.x;
    if (i < n) out[i] = (bf16)in[i];
}

// ---------------------------------------------------------------------------
// Wv [d][c] bf16 -> wvt [c][d] bf16  (512x512 transpose)
// ---------------------------------------------------------------------------
__global__ __launch_bounds__(256) void wvt_kernel(
    const bf16* __restrict__ wv, bf16* __restrict__ wvt)
{
    const int c0 = blockIdx.x * 64;
    const int d0 = blockIdx.y * 64;
    __shared__ bf16 tl[64][72];
    const int t = threadIdx.x;

    #pragma unroll
    for (int i = 0; i < 2; ++i) {
        const int lin = t + 256 * i;     // 0..511
        const int row = lin >> 3;        // d-local
        const int c8  = (lin & 7) * 8;
        *(bf16x8*)&tl[row][c8] = *(const bf16x8*)(wv + (size_t)(d0 + row) * CH + c0 + c8);
    }
    __syncthreads();
    #pragma unroll
    for (int i = 0; i < 2; ++i) {
        const int lin  = t + 256 * i;
        const int crow = lin >> 3;       // c-local
        const int d8   = (lin & 7) * 8;
        bf16x8 v;
        #pragma unroll
        for (int j = 0; j < 8; ++j) v[j] = tl[d8 + j][crow];
        *(bf16x8*)(wvt + (size_t)(c0 + crow) * CH + d0 + d8) = v;
    }
}

// ---------------------------------------------------------------------------
// x [b][512][4096] fp32 -> xt [b][4096][512] bf16 (transpose),
//                          xb [b][512][4096] bf16 (flat),
//                          xpart[b][c][ntile] fp32 row partial sums.
// ---------------------------------------------------------------------------
__global__ __launch_bounds__(256) void transpose_convert_dual_kernel(
    const float* __restrict__ x, bf16* __restrict__ xt, bf16* __restrict__ xb,
    float* __restrict__ xpart)
{
    const int b  = blockIdx.z;
    const int n0 = blockIdx.x * 64;
    const int c0 = blockIdx.y * 64;
    __shared__ float tile[64][65];
    const int t = threadIdx.x;
    const float* xp = x + (size_t)b * CH * NPIX;

    #pragma unroll
    for (int i = 0; i < 4; ++i) {
        const int lin = t + 256 * i;
        const int r   = lin >> 4;
        const int c4  = (lin & 15) * 4;
        const float4 v = *(const float4*)(xp + (size_t)(c0 + r) * 4096 + n0 + c4);
        tile[r][c4 + 0] = v.x; tile[r][c4 + 1] = v.y;
        tile[r][c4 + 2] = v.z; tile[r][c4 + 3] = v.w;
    }
    __syncthreads();

    // fp32 row partial sums (exact x, deterministic tree)
    {
        const int r = t >> 2, q = t & 3;
        float s = 0.f;
        #pragma unroll
        for (int j = 0; j < 16; ++j) s += tile[r][q * 16 + j];
        s += __shfl_xor(s, 1);
        s += __shfl_xor(s, 2);
        if ((t & 3) == 0)
            xpart[(((size_t)b * CH + c0 + r) << 6) + blockIdx.x] = s;
    }

    bf16* op = xt + (size_t)b * NPIX * CH;
    bf16* fb = xb + (size_t)b * CH * NPIX;
    #pragma unroll
    for (int i = 0; i < 2; ++i) {
        const int lin = t + 256 * i;
        {
            const int n  = lin >> 3;
            const int c8 = (lin & 7) * 8;
            bf16x8 v;
            #pragma unroll
            for (int jj = 0; jj < 8; ++jj) v[jj] = (bf16)tile[c8 + jj][n];
            *(bf16x8*)(op + (size_t)(n0 + n) * CH + c0 + c8) = v;
        }
        {
            const int r  = lin >> 3;
            const int n8 = (lin & 7) * 8;
            bf16x8 v;
            #pragma unroll
            for (int jj = 0; jj < 8; ++jj) v[jj] = (bf16)tile[r][n8 + jj];
            *(bf16x8*)(fb + (size_t)(c0 + r) * NPIX + n0 + n8) = v;
        }
    }
}

// ---------------------------------------------------------------------------
// xsum[b][c] = sum over 64 tile-partials
// ---------------------------------------------------------------------------
__global__ __launch_bounds__(256) void xsum_reduce_kernel(
    const float* __restrict__ xpart, float* __restrict__ xs)
{
    const int gi = blockIdx.x * 256 + threadIdx.x;   // < 4096
    const float* p = xpart + ((size_t)gi << 6);
    float s = 0.f;
    #pragma unroll
    for (int j = 0; j < 16; ++j) {
        const float4 v = *(const float4*)(p + j * 4);
        s += v.x + v.y + v.z + v.w;
    }
    xs[gi] = s;
}

// ---------------------------------------------------------------------------
// Gram split-K partial: gpart[b*4+s][m][n] = sum_{n' in split} xb[m,n']xb[n,n']
// ---------------------------------------------------------------------------
__global__ __launch_bounds__(256) void gram_partial_kernel(
    const bf16* __restrict__ xb, float* __restrict__ gpart)
{
    const int bs = blockIdx.z;
    const int b = bs >> 2, s = bs & 3;
    const int m0 = blockIdx.y * 128;
    const int n0 = blockIdx.x * 128;
    const bf16* Xp = xb + (size_t)b * CH * NPIX;
    const int kbase = s * 1024;

    __shared__ bf16 smem[16384];

    const int t    = threadIdx.x;
    const int lane = t & 63;
    const int wave = t >> 6;
    const int wr   = wave >> 1, wc = wave & 1;

    f32x4 acc[4][4];
    const f32x4 zf = {0.f, 0.f, 0.f, 0.f};
    #pragma unroll
    for (int i = 0; i < 4; ++i)
        #pragma unroll
        for (int j = 0; j < 4; ++j) acc[i][j] = zf;

    auto STAGE = [&](int p, int k0) {
        #pragma unroll
        for (int i = 0; i < 2; ++i) {
            const int c   = t + 256 * i;
            const int row = c >> 2;
            const int kb  = ((c & 3) ^ ((row >> 1) & 3)) * 8;
            __builtin_amdgcn_global_load_lds(
                (const AS1 void*)(Xp + (size_t)(m0 + row) * NPIX + kbase + k0 + kb),
                (AS3 void*)(smem + p * 8192 + c * 8), 16, 0, 0);
            __builtin_amdgcn_global_load_lds(
                (const AS1 void*)(Xp + (size_t)(n0 + row) * NPIX + kbase + k0 + kb),
                (AS3 void*)(smem + p * 8192 + 4096 + c * 8), 16, 0, 0);
        }
    };

    STAGE(0, 0);
    __syncthreads();
    int cur = 0;

    for (int kt = 0; kt < 1024 / 32; ++kt) {
        if (kt < 1024 / 32 - 1) STAGE(cur ^ 1, (kt + 1) * 32);

        const bf16* AsP = smem + cur * 8192;
        const bf16* BsP = AsP + 4096;
        bf16x8 af[4], bfv[4];
        #pragma unroll
        for (int i = 0; i < 4; ++i) {
            const int ar = wr * 64 + i * 16 + (lane & 15);
            const int ja = (lane >> 4) ^ ((ar >> 1) & 3);
            af[i]  = *(const bf16x8*)(AsP + ar * 32 + ja * 8);
            const int br = wc * 64 + i * 16 + (lane & 15);
            const int jb = (lane >> 4) ^ ((br >> 1) & 3);
            bfv[i] = *(const bf16x8*)(BsP + br * 32 + jb * 8);
        }
        #pragma unroll
        for (int i = 0; i < 4; ++i)
            #pragma unroll
            for (int j = 0; j < 4; ++j)
                acc[i][j] = __builtin_amdgcn_mfma_f32_16x16x32_bf16(
                    af[i], bfv[j], acc[i][j], 0, 0, 0);

        __syncthreads();
        cur ^= 1;
    }

    float* Gp = gpart + (size_t)bs * CH * CH;
    #pragma unroll
    for (int i = 0; i < 4; ++i) {
        const int mb = m0 + wr * 64 + i * 16 + (lane >> 4) * 4;
        #pragma unroll
        for (int r = 0; r < 4; ++r) {
            const int m = mb + r;
            #pragma unroll
            for (int j = 0; j < 4; ++j) {
                const int n = n0 + wc * 64 + j * 16 + (lane & 15);
                Gp[(size_t)m * CH + n] = acc[i][j][r];
            }
        }
    }
}

// ---------------------------------------------------------------------------
// Gpair[b][n][0..511]=hi, [512..1023]=lo  of  sum_s gpart
// ---------------------------------------------------------------------------
__global__ __launch_bounds__(256) void gram_reduce_kernel(
    const float* __restrict__ gpart, bf16* __restrict__ Gpair)
{
    const int gi = blockIdx.x * 256 + threadIdx.x;   // < 8*262144
    const int b = gi >> 18, r = gi & 262143;
    const int n = r >> 9, k = r & 511;
    const float* p = gpart + (size_t)(b * 4) * 262144 + r;
    const float s = p[0] + p[262144] + p[2 * 262144] + p[3 * 262144];
    const bf16 hi = (bf16)s;
    const bf16 lo = (bf16)(s - (float)hi);
    bf16* gp = Gpair + ((size_t)b * CH + n) * 1024;
    gp[k] = hi;
    gp[512 + k] = lo;
}

// ---------------------------------------------------------------------------
// T2 = Wq · (Ghi + Glo): K=1024 GEMM (Wq k-index &511), hi/lo bf16 pair out.
// ---------------------------------------------------------------------------
__global__ __launch_bounds__(256) void t2_gemm_kernel(
    const bf16* __restrict__ Wq, const bf16* __restrict__ Gpair,
    bf16* __restrict__ T2pair)
{
    const int b  = blockIdx.z;
    const int m0 = blockIdx.y * 128;
    const int n0 = blockIdx.x * 128;
    const bf16* Bp = Gpair + (size_t)b * CH * 1024;

    __shared__ bf16 smem[16384];

    const int t    = threadIdx.x;
    const int lane = t & 63;
    const int wave = t >> 6;
    const int wr   = wave >> 1, wc = wave & 1;

    f32x4 acc[4][4];
    const f32x4 zf = {0.f, 0.f, 0.f, 0.f};
    #pragma unroll
    for (int i = 0; i < 4; ++i)
        #pragma unroll
        for (int j = 0; j < 4; ++j) acc[i][j] = zf;

    auto STAGE = [&](int p, int k0) {
        #pragma unroll
        for (int i = 0; i < 2; ++i) {
            const int c   = t + 256 * i;
            const int row = c >> 2;
            const int kb  = ((c & 3) ^ ((row >> 1) & 3)) * 8;
            __builtin_amdgcn_global_load_lds(
                (const AS1 void*)(Wq + (size_t)(m0 + row) * KDEPTH + ((k0 + kb) & 511)),
                (AS3 void*)(smem + p * 8192 + c * 8), 16, 0, 0);
            __builtin_amdgcn_global_load_lds(
                (const AS1 void*)(Bp + (size_t)(n0 + row) * 1024 + k0 + kb),
                (AS3 void*)(smem + p * 8192 + 4096 + c * 8), 16, 0, 0);
        }
    };

    STAGE(0, 0);
    __syncthreads();
    int cur = 0;

    for (int kt = 0; kt < 1024 / 32; ++kt) {
        if (kt < 1024 / 32 - 1) STAGE(cur ^ 1, (kt + 1) * 32);

        const bf16* AsP = smem + cur * 8192;
        const bf16* BsP = AsP + 4096;
        bf16x8 af[4], bfv[4];
        #pragma unroll
        for (int i = 0; i < 4; ++i) {
            const int ar = wr * 64 + i * 16 + (lane & 15);
            const int ja = (lane >> 4) ^ ((ar >> 1) & 3);
            af[i]  = *(const bf16x8*)(AsP + ar * 32 + ja * 8);
            const int br = wc * 64 + i * 16 + (lane & 15);
            const int jb = (lane >> 4) ^ ((br >> 1) & 3);
            bfv[i] = *(const bf16x8*)(BsP + br * 32 + jb * 8);
        }
        #pragma unroll
        for (int i = 0; i < 4; ++i)
            #pragma unroll
            for (int j = 0; j < 4; ++j)
                acc[i][j] = __builtin_amdgcn_mfma_f32_16x16x32_bf16(
                    af[i], bfv[j], acc[i][j], 0, 0, 0);

        __syncthreads();
        cur ^= 1;
    }

    bf16* Tp = T2pair + (size_t)b * CH * 1024;
    #pragma unroll
    for (int i = 0; i < 4; ++i) {
        const int mb = m0 + wr * 64 + i * 16 + (lane >> 4) * 4;
        #pragma unroll
        for (int r = 0; r < 4; ++r) {
            const int m = mb + r;
            #pragma unroll
            for (int j = 0; j < 4; ++j) {
                const int n = n0 + wc * 64 + j * 16 + (lane & 15);
                const float s = acc[i][j][r];
                const bf16 hi = (bf16)s;
                Tp[(size_t)m * 1024 + n] = hi;
                Tp[(size_t)m * 1024 + 512 + n] = (bf16)(s - (float)hi);
            }
        }
    }
}

// ---------------------------------------------------------------------------
// Generic 128x128 GEMM, K=512: Cb!=null -> bf16 out, else fp32 Cf (+bias).
// bias indexed [b*bias_bstride + m].
// ---------------------------------------------------------------------------
__global__ __launch_bounds__(256) void gemm128_kernel(
    const bf16* __restrict__ A, const bf16* __restrict__ Bt,
    const float* __restrict__ bias, size_t bias_bstride,
    float* __restrict__ Cf, bf16* __restrict__ Cb,
    int ncols, int c_rows, size_t a_bstride, size_t bt_bstride)
{
    const int b  = blockIdx.z;
    const int m0 = blockIdx.y * 128;
    const int n0 = blockIdx.x * 128;
    const bf16* Ap = A  + (size_t)b * a_bstride;
    const bf16* Bp = Bt + (size_t)b * bt_bstride;

    __shared__ bf16 smem[16384];

    const int t    = threadIdx.x;
    const int lane = t & 63;
    const int wave = t >> 6;
    const int wr   = wave >> 1, wc = wave & 1;

    f32x4 acc[4][4];
    const f32x4 zf = {0.f, 0.f, 0.f, 0.f};
    #pragma unroll
    for (int i = 0; i < 4; ++i)
        #pragma unroll
        for (int j = 0; j < 4; ++j) acc[i][j] = zf;

    auto STAGE = [&](int p, int k0) {
        #pragma unroll
        for (int i = 0; i < 2; ++i) {
            const int c   = t + 256 * i;
            const int row = c >> 2;
            const int kb  = ((c & 3) ^ ((row >> 1) & 3)) * 8;
            __builtin_amdgcn_global_load_lds(
                (const AS1 void*)(Ap + (size_t)(m0 + row) * KDEPTH + k0 + kb),
                (AS3 void*)(smem + p * 8192 + c * 8), 16, 0, 0);
            __builtin_amdgcn_global_load_lds(
                (const AS1 void*)(Bp + (size_t)(n0 + row) * KDEPTH + k0 + kb),
                (AS3 void*)(smem + p * 8192 + 4096 + c * 8), 16, 0, 0);
        }
    };

    STAGE(0, 0);
    __syncthreads();
    int cur = 0;

    for (int kt = 0; kt < KDEPTH / 32; ++kt) {
        if (kt < KDEPTH / 32 - 1) STAGE(cur ^ 1, (kt + 1) * 32);

        const bf16* AsP = smem + cur * 8192;
        const bf16* BsP = AsP + 4096;
        bf16x8 af[4], bfv[4];
        #pragma unroll
        for (int i = 0; i < 4; ++i) {
            const int ar = wr * 64 + i * 16 + (lane & 15);
            const int ja = (lane >> 4) ^ ((ar >> 1) & 3);
            af[i]  = *(const bf16x8*)(AsP + ar * 32 + ja * 8);
            const int br = wc * 64 + i * 16 + (lane & 15);
            const int jb = (lane >> 4) ^ ((br >> 1) & 3);
            bfv[i] = *(const bf16x8*)(BsP + br * 32 + jb * 8);
        }
        #pragma unroll
        for (int i = 0; i < 4; ++i)
            #pragma unroll
            for (int j = 0; j < 4; ++j)
                acc[i][j] = __builtin_amdgcn_mfma_f32_16x16x32_bf16(
                    af[i], bfv[j], acc[i][j], 0, 0, 0);

        __syncthreads();
        cur ^= 1;
    }

    #pragma unroll
    for (int i = 0; i < 4; ++i) {
        const int mb = m0 + wr * 64 + i * 16 + (lane >> 4) * 4;
        #pragma unroll
        for (int r = 0; r < 4; ++r) {
            const int m  = mb + r;
            const float bv = bias ? bias[b * bias_bstride + m] : 0.f;
            #pragma unroll
            for (int j = 0; j < 4; ++j) {
                const int n = n0 + wc * 64 + j * 16 + (lane & 15);
                if (Cb) Cb[(size_t)b * c_rows * ncols + (size_t)m * ncols + n] =
                            (bf16)(acc[i][j][r] + bv);
                else    Cf[(size_t)b * c_rows * ncols + (size_t)m * ncols + n] =
                            acc[i][j][r] + bv;
            }
        }
    }
}

// ---------------------------------------------------------------------------
// S + softmax (unchanged, R13-verified): S = (T2hi+T2lo)·Wk^T + rank-1 bias.
// ---------------------------------------------------------------------------
__global__ __launch_bounds__(256) void s_softmax_kernel(
    const bf16* __restrict__ T2pair, const bf16* __restrict__ wfull,
    const float* __restrict__ qkv_b, const float* __restrict__ xsum,
    float* __restrict__ attn)
{
    const int bh = blockIdx.x;
    const int b = bh >> 3, h = bh & 7;
    const bf16* qbase = T2pair + ((size_t)b * CH + h * HDIM) * 1024;
    const bf16* kbase = wfull + (size_t)(CH + h * HDIM) * CH;

    __shared__ bf16 smem[16384];
    __shared__ float xs[512], qv[64], kv[64], bqs[64], bks[64];

    const int t    = threadIdx.x;
    const int lane = t & 63;
    const int wave = t >> 6;

    for (int i = t; i < 512; i += 256) xs[i] = xsum[b * CH + i];
    if (t < 64) {
        bqs[t] = qkv_b[h * HDIM + t];
        bks[t] = qkv_b[CH + h * HDIM + t];
    }
    __syncthreads();
    if (t < 128) {
        const int e = t & 63;
        const bf16* wrow = wfull + (size_t)((t < 64 ? 0 : CH) + h * HDIM + e) * CH;
        float s = 0.f;
        for (int c = 0; c < 512; ++c) s += (float)wrow[c] * xs[c];
        if (t < 64) qv[e] = s;
        else        kv[e] = s + 4096.f * bks[e];
    }

    f32x4 acc[4];
    const f32x4 zf = {0.f, 0.f, 0.f, 0.f};
    #pragma unroll
    for (int j = 0; j < 4; ++j) acc[j] = zf;

    auto STAGE = [&](int p, int k0) {
        #pragma unroll
        for (int i = 0; i < 2; ++i) {
            const int c   = t + 256 * i;
            const int row = c >> 3;
            const int nb  = ((c & 7) ^ (row & 7)) * 8;
            __builtin_amdgcn_global_load_lds(
                (const AS1 void*)(qbase + (size_t)row * 1024 + k0 + nb),
                (AS3 void*)(smem + p * 8192 + c * 8), 16, 0, 0);
            __builtin_amdgcn_global_load_lds(
                (const AS1 void*)(kbase + (size_t)row * CH + ((k0 + nb) & 511)),
                (AS3 void*)(smem + p * 8192 + 4096 + c * 8), 16, 0, 0);
        }
    };

    STAGE(0, 0);
    __syncthreads();
    int cur = 0;

    for (int nc = 0; nc < 16; ++nc) {
        if (nc < 15) STAGE(cur ^ 1, (nc + 1) * 64);

        const bf16* Qs = smem + cur * 8192;
        const bf16* Ks = Qs + 4096;
        #pragma unroll
        for (int ks = 0; ks < 2; ++ks) {
            const int dr = wave * 16 + (lane & 15);
            const int ja = (ks * 4 + (lane >> 4)) ^ (dr & 7);
            const bf16x8 af = *(const bf16x8*)(Qs + dr * 64 + ja * 8);
            #pragma unroll
            for (int j = 0; j < 4; ++j) {
                const int er = j * 16 + (lane & 15);
                const int jb = (ks * 4 + (lane >> 4)) ^ (er & 7);
                const bf16x8 bf_ = *(const bf16x8*)(Ks + er * 64 + jb * 8);
                acc[j] = __builtin_amdgcn_mfma_f32_16x16x32_bf16(af, bf_, acc[j], 0, 0, 0);
            }
        }
        __syncthreads();
        cur ^= 1;
    }

    #pragma unroll
    for (int r = 0; r < 4; ++r) {
        const int d = wave * 16 + (lane >> 4) * 4 + r;
        float row4[4];
        #pragma unroll
        for (int j = 0; j < 4; ++j) {
            const int e = j * 16 + (lane & 15);
            row4[j] = acc[j][r] + bqs[d] * kv[e] + qv[d] * bks[e];
        }
        float m = fmaxf(fmaxf(row4[0], row4[1]), fmaxf(row4[2], row4[3]));
        m = fmaxf(m, __shfl_xor(m, 1));
        m = fmaxf(m, __shfl_xor(m, 2));
        m = fmaxf(m, __shfl_xor(m, 4));
        m = fmaxf(m, __shfl_xor(m, 8));
        float p4[4], sum = 0.f;
        #pragma unroll
        for (int j = 0; j < 4; ++j) { p4[j] = __expf((row4[j] - m) * SCALE); sum += p4[j]; }
        sum += __shfl_xor(sum, 1);
        sum += __shfl_xor(sum, 2);
        sum += __shfl_xor(sum, 4);
        sum += __shfl_xor(sum, 8);
        const float inv = 1.f / sum;
        #pragma unroll
        for (int j = 0; j < 4; ++j) {
            const int e = j * 16 + (lane & 15);
            attn[((size_t)bh * 64 + d) * 64 + e] = p4[j] * inv;
        }
    }
}

// ---------------------------------------------------------------------------
// attn_mean[b][d][e] = mean_h attn[b][h][d][e]
// ---------------------------------------------------------------------------
__global__ __launch_bounds__(256) void attn_mean_kernel(
    const float* __restrict__ attn, float* __restrict__ om)
{
    const int idx = blockIdx.x * 256 + threadIdx.x;
    const int b = idx >> 12, de = idx & 4095;
    float s = 0.f;
    #pragma unroll
    for (int h = 0; h < 8; ++h)
        s += attn[(((size_t)b * 8 + h) << 12) + de];
    om[idx] = s * 0.125f;
}

// ---------------------------------------------------------------------------
// W'[b][o][h*64+e] = sum_d proj_w[o][h*64+d] * attn[b,h,d,e]   (fp32 -> bf16)
// ---------------------------------------------------------------------------
__global__ __launch_bounds__(256) void wprime_kernel(
    const float* __restrict__ proj_w, const float* __restrict__ attn,
    bf16* __restrict__ wp)
{
    const int o0 = blockIdx.x * 64;
    const int h  = blockIdx.y;
    const int b  = blockIdx.z;

    __shared__ float ws[64][65];
    __shared__ float as_[64][65];

    const int t = threadIdx.x;
    #pragma unroll
    for (int i = 0; i < 4; ++i) {
        const int lin = t + 256 * i;
        const int r   = lin >> 4;
        const int c4  = (lin & 15) * 4;
        const float4 wv = *(const float4*)(proj_w + (size_t)(o0 + r) * CH + h * HDIM + c4);
        ws[r][c4 + 0] = wv.x; ws[r][c4 + 1] = wv.y;
        ws[r][c4 + 2] = wv.z; ws[r][c4 + 3] = wv.w;
        const float4 av = *(const float4*)(attn + (((size_t)(b * 8 + h) * 64) + r) * 64 + c4);
        as_[r][c4 + 0] = av.x; as_[r][c4 + 1] = av.y;
        as_[r][c4 + 2] = av.z; as_[r][c4 + 3] = av.w;
    }
    __syncthreads();

    const int tx = t & 15, ty = t >> 4;
    const int to = ty * 4, te = tx * 4;
    float acc[4][4] = {};
    for (int d = 0; d < 64; ++d) {
        float a[4], bb[4];
        #pragma unroll
        for (int i = 0; i < 4; ++i) a[i]  = ws[to + i][d];
        #pragma unroll
        for (int j = 0; j < 4; ++j) bb[j] = as_[d][te + j];
        #pragma unroll
        for (int i = 0; i < 4; ++i)
            #pragma unroll
            for (int j = 0; j < 4; ++j)
                acc[i][j] = fmaf(a[i], bb[j], acc[i][j]);
    }

    bf16* wb = wp + (size_t)b * CH * CH;
    #pragma unroll
    for (int i = 0; i < 4; ++i)
        #pragma unroll
        for (int j = 0; j < 4; ++j)
            wb[(size_t)(o0 + to + i) * CH + h * HDIM + te + j] = (bf16)acc[i][j];
}

// ---------------------------------------------------------------------------
// bias2[b][o] = sum_d W'[b][o][d] * bv[d] + pb[o]
// ---------------------------------------------------------------------------
__global__ __launch_bounds__(256) void bias2_kernel(
    const bf16* __restrict__ wp, const float* __restrict__ bv,
    const float* __restrict__ pb, float* __restrict__ bias2)
{
    const int idx = blockIdx.x * 256 + threadIdx.x;   // < 4096
    const int b = idx >> 9, o = idx & 511;
    const bf16* wr = wp + ((size_t)b * CH + o) * CH;
    float s = 0.f;
    for (int d = 0; d < 512; ++d) s += (float)wr[d] * bv[d];
    bias2[idx] = s + pb[o];
}

// ---------------------------------------------------------------------------
extern "C" void kernel_launch(void* const* d_in, const int* in_sizes, int n_in,
                              void* d_out, int out_size, void* d_ws, size_t ws_size,
                              hipStream_t stream)
{
    (void)in_sizes; (void)n_in; (void)out_size;
    const float* x      = (const float*)d_in[0];
    const float* qkv_w  = (const float*)d_in[1];
    const float* qkv_b  = (const float*)d_in[2];
    const float* proj_w = (const float*)d_in[3];
    const float* proj_b = (const float*)d_in[4];

    float* out       = (float*)d_out;
    float* attn_mean = out + (size_t)BATCH * CH * NPIX;

    const size_t xt_bytes    = (size_t)BATCH * NPIX * CH * 2;          // 32 MiB
    const size_t xb_bytes    = (size_t)BATCH * CH * NPIX * 2;          // 32 MiB
    const size_t gpart_bytes = (size_t)BATCH * GSPLIT * CH * CH * 4;   // 32 MiB
    const size_t G_bytes     = (size_t)BATCH * CH * 1024 * 2;          //  8 MiB
    const size_t T2_bytes    = (size_t)BATCH * CH * 1024 * 2;          //  8 MiB
    const size_t wq_bytes    = (size_t)OC3 * KDEPTH * 2;               // 1.5 MiB
    const size_t attn_bytes  = (size_t)BATCH * HEADS * HDIM * HDIM * 4;//  1 MiB
    const size_t wp_bytes    = (size_t)BATCH * CH * CH * 2;            //  4 MiB (W')
    const size_t wpp_bytes   = (size_t)BATCH * CH * CH * 2;            //  4 MiB (W'')
    const size_t wvt_bytes   = (size_t)CH * CH * 2;                    // 0.5 MiB
    const size_t xpart_bytes = (size_t)BATCH * CH * 64 * 4;            // 1 MiB
    const size_t xsum_bytes  = (size_t)BATCH * CH * 4;                 // 16 KiB
    const size_t b2_bytes    = (size_t)BATCH * CH * 4;                 // 16 KiB
    const size_t need = xt_bytes + xb_bytes + gpart_bytes + G_bytes + T2_bytes +
                        wq_bytes + attn_bytes + wp_bytes + wpp_bytes + wvt_bytes +
                        xpart_bytes + xsum_bytes + b2_bytes;
    if (ws_size < need) {
        fprintf(stderr, "[kernel_launch] ws_size=%zu < need=%zu — abort\n", ws_size, need);
        fflush(stderr);
        return;
    }

    char* p = (char*)d_ws;
    bf16*  xt     = (bf16*)p;             p += xt_bytes;
    bf16*  xb     = (bf16*)p;             p += xb_bytes;
    float* gpart  = (float*)p;            p += gpart_bytes;
    bf16*  Gpair  = (bf16*)p;             p += G_bytes;
    bf16*  T2pair = (bf16*)p;             p += T2_bytes;
    bf16*  wq_b   = (bf16*)p;             p += wq_bytes;
    float* attn   = (float*)p;            p += attn_bytes;
    bf16*  wprime = (bf16*)p;             p += wp_bytes;
    bf16*  wpp    = (bf16*)p;             p += wpp_bytes;
    bf16*  wvt    = (bf16*)p;             p += wvt_bytes;
    float* xpart  = (float*)p;            p += xpart_bytes;
    float* xsum   = (float*)p;            p += xsum_bytes;
    float* bias2  = (float*)p;

    // 0) weight convert (Wq, Wk, Wv) + Wv transpose
    convert_bf16_kernel<<<dim3((OC3 * KDEPTH + 255) / 256), 256, 0, stream>>>(
        qkv_w, wq_b, OC3 * KDEPTH);
    wvt_kernel<<<dim3(8, 8), 256, 0, stream>>>(wq_b + (size_t)2 * CH * KDEPTH, wvt);

    // 1) x -> xt + xb + xsum partials
    transpose_convert_dual_kernel<<<dim3(NPIX / 64, CH / 64, BATCH), 256, 0, stream>>>(
        x, xt, xb, xpart);
    xsum_reduce_kernel<<<dim3(BATCH * CH / 256), 256, 0, stream>>>(xpart, xsum);

    // 2) Gram: G = x x^T, split-K, then hi/lo reduce
    gram_partial_kernel<<<dim3(CH / 128, CH / 128, BATCH * GSPLIT), 256, 0, stream>>>(
        xb, gpart);
    gram_reduce_kernel<<<dim3(BATCH * CH * CH / 256), 256, 0, stream>>>(gpart, Gpair);

    // 3) T2 = Wq · G
    t2_gemm_kernel<<<dim3(CH / 128, CH / 128, BATCH), 256, 0, stream>>>(
        wq_b, Gpair, T2pair);

    // 4) S = T2 · Wk^T + rank-1, softmax -> attn
    s_softmax_kernel<<<dim3(BATCH * HEADS), 256, 0, stream>>>(
        T2pair, wq_b, qkv_b, xsum, attn);

    // 5) attn mean (output 1)
    attn_mean_kernel<<<dim3(BATCH * HDIM * HDIM / 256), 256, 0, stream>>>(attn, attn_mean);

    // 6) W' = proj_w · blockdiag(attn)
    wprime_kernel<<<dim3(CH / 64, HEADS, BATCH), 256, 0, stream>>>(proj_w, attn, wprime);

    // 7) W'' = W' · Wv (bf16), bias'' = W'·bv + pb
    gemm128_kernel<<<dim3(CH / 128, CH / 128, BATCH), 256, 0, stream>>>(
        wprime, wvt, nullptr, 0, nullptr, wpp, CH, CH, (size_t)CH * CH, 0);
    bias2_kernel<<<dim3(BATCH * CH / 256), 256, 0, stream>>>(
        wprime, qkv_b + 2 * CH, proj_b, bias2);

    // 8) out = W''_b · x + bias''   (single remaining big GEMM)
    gemm128_kernel<<<dim3(NPIX / 128, CH / 128, BATCH), 256, 0, stream>>>(
        wpp, xt, bias2, CH, out, nullptr, NPIX, CH, (size_t)CH * CH,
        (size_t)NPIX * KDEPTH);
}

// Round 15
// 167.948 us; speedup vs baseline: 1.1264x; 1.1264x over previous
//
#include <hip/hip_runtime.h>
#include <cstdio>
#include <cstdint>

// Problem constants
#define BATCH 8
#define CH    512
#define OC3   1536      // 3*CH
#define QKROWS 1024     // Q+K channel rows (bf16)
#define NPIX  4096      // 64*64
#define HEADS 8
#define HDIM  64
#define KDEPTH 512
#define SCALE 0.125f    // 64^-0.5
#define NSPLIT 16       // split-K factor for QK^T (256 n per split)

typedef __bf16 bf16;
typedef __bf16 bf16x4 __attribute__((ext_vector_type(4)));
typedef __bf16 bf16x8 __attribute__((ext_vector_type(8)));
typedef float  f32x4  __attribute__((ext_vector_type(4)));

#define AS1 __attribute__((address_space(1)))
#define AS3 __attribute__((address_space(3)))

// ---------------------------------------------------------------------------
// fp32 -> bf16 flat convert (weights)
// ---------------------------------------------------------------------------
__global__ __launch_bounds__(256) void convert_bf16_kernel(
    const float* __restrict__ in, bf16* __restrict__ out, int n)
{
    const int i = blockIdx.x * 256 + threadIdx.x;
    if (i < n) out[i] = (bf16)in[i];
}

// ---------------------------------------------------------------------------
// Wv [d][c] bf16 -> wvt [c][d] bf16  (512x512 transpose)   [R14-verified]
// ---------------------------------------------------------------------------
__global__ __launch_bounds__(256) void wvt_kernel(
    const bf16* __restrict__ wv, bf16* __restrict__ wvt)
{
    const int c0 = blockIdx.x * 64;
    const int d0 = blockIdx.y * 64;
    __shared__ bf16 tl[64][72];
    const int t = threadIdx.x;

    #pragma unroll
    for (int i = 0; i < 2; ++i) {
        const int lin = t + 256 * i;
        const int row = lin >> 3;
        const int c8  = (lin & 7) * 8;
        *(bf16x8*)&tl[row][c8] = *(const bf16x8*)(wv + (size_t)(d0 + row) * CH + c0 + c8);
    }
    __syncthreads();
    #pragma unroll
    for (int i = 0; i < 2; ++i) {
        const int lin  = t + 256 * i;
        const int crow = lin >> 3;
        const int d8   = (lin & 7) * 8;
        bf16x8 v;
        #pragma unroll
        for (int j = 0; j < 8; ++j) v[j] = tl[d8 + j][crow];
        *(bf16x8*)(wvt + (size_t)(c0 + crow) * CH + d0 + d8) = v;
    }
}

// ---------------------------------------------------------------------------
// x [b][512][4096] fp32 -> xt [b][4096][512] bf16 (transpose)  [R10-verified]
// ---------------------------------------------------------------------------
__global__ __launch_bounds__(256) void transpose_convert_kernel(
    const float* __restrict__ src, bf16* __restrict__ dst)
{
    const int b  = blockIdx.z;
    const int n0 = blockIdx.x * 64;
    const int c0 = blockIdx.y * 64;
    __shared__ float tile[64][65];
    const int t = threadIdx.x;
    const float* xp = src + (size_t)b * CH * NPIX;

    #pragma unroll
    for (int i = 0; i < 4; ++i) {
        const int lin = t + 256 * i;
        const int r   = lin >> 4;
        const int c4  = (lin & 15) * 4;
        const float4 v = *(const float4*)(xp + (size_t)(c0 + r) * 4096 + n0 + c4);
        tile[r][c4 + 0] = v.x; tile[r][c4 + 1] = v.y;
        tile[r][c4 + 2] = v.z; tile[r][c4 + 3] = v.w;
    }
    __syncthreads();

    bf16* op = dst + (size_t)b * NPIX * CH;
    #pragma unroll
    for (int i = 0; i < 2; ++i) {
        const int lin = t + 256 * i;
        const int n   = lin >> 3;
        const int c8  = (lin & 7) * 8;
        bf16x8 v;
        #pragma unroll
        for (int jj = 0; jj < 8; ++jj) v[jj] = (bf16)tile[c8 + jj][n];
        *(bf16x8*)(op + (size_t)(n0 + n) * CH + c0 + c8) = v;
    }
}

// ---------------------------------------------------------------------------
// QK GEMM: qk[b][m][n] bf16 = sum_k Wqk[m][k]*xt[b][n][k] + bias[m]
// 128x128 tile, BK=32, 2-phase dbuf + chunk XOR swizzle  [R10-verified]
// ---------------------------------------------------------------------------
__global__ __launch_bounds__(256) void gemm_qk_kernel(
    const bf16* __restrict__ A, const bf16* __restrict__ Bt,
    const float* __restrict__ bias, bf16* __restrict__ qkb)
{
    const int b  = blockIdx.z;
    const int m0 = blockIdx.y * 128;
    const int n0 = blockIdx.x * 128;
    const bf16* Ap = A;
    const bf16* Bp = Bt + (size_t)b * NPIX * KDEPTH;

    __shared__ bf16 smem[16384];

    const int t    = threadIdx.x;
    const int lane = t & 63;
    const int wave = t >> 6;
    const int wr   = wave >> 1, wc = wave & 1;

    f32x4 acc[4][4];
    const f32x4 zf = {0.f, 0.f, 0.f, 0.f};
    #pragma unroll
    for (int i = 0; i < 4; ++i)
        #pragma unroll
        for (int j = 0; j < 4; ++j) acc[i][j] = zf;

    auto STAGE = [&](int p, int k0) {
        #pragma unroll
        for (int i = 0; i < 2; ++i) {
            const int c   = t + 256 * i;
            const int row = c >> 2;
            const int kb  = ((c & 3) ^ ((row >> 1) & 3)) * 8;
            __builtin_amdgcn_global_load_lds(
                (const AS1 void*)(Ap + (size_t)(m0 + row) * KDEPTH + k0 + kb),
                (AS3 void*)(smem + p * 8192 + c * 8), 16, 0, 0);
            __builtin_amdgcn_global_load_lds(
                (const AS1 void*)(Bp + (size_t)(n0 + row) * KDEPTH + k0 + kb),
                (AS3 void*)(smem + p * 8192 + 4096 + c * 8), 16, 0, 0);
        }
    };

    STAGE(0, 0);
    __syncthreads();
    int cur = 0;

    for (int kt = 0; kt < KDEPTH / 32; ++kt) {
        if (kt < KDEPTH / 32 - 1) STAGE(cur ^ 1, (kt + 1) * 32);

        const bf16* AsP = smem + cur * 8192;
        const bf16* BsP = AsP + 4096;
        bf16x8 af[4], bfv[4];
        #pragma unroll
        for (int i = 0; i < 4; ++i) {
            const int ar = wr * 64 + i * 16 + (lane & 15);
            const int ja = (lane >> 4) ^ ((ar >> 1) & 3);
            af[i]  = *(const bf16x8*)(AsP + ar * 32 + ja * 8);
            const int br = wc * 64 + i * 16 + (lane & 15);
            const int jb = (lane >> 4) ^ ((br >> 1) & 3);
            bfv[i] = *(const bf16x8*)(BsP + br * 32 + jb * 8);
        }
        #pragma unroll
        for (int i = 0; i < 4; ++i)
            #pragma unroll
            for (int j = 0; j < 4; ++j)
                acc[i][j] = __builtin_amdgcn_mfma_f32_16x16x32_bf16(
                    af[i], bfv[j], acc[i][j], 0, 0, 0);

        __syncthreads();
        cur ^= 1;
    }

    bf16* Qp = qkb + (size_t)b * QKROWS * NPIX;
    #pragma unroll
    for (int i = 0; i < 4; ++i) {
        const int mb = m0 + wr * 64 + i * 16 + (lane >> 4) * 4;
        #pragma unroll
        for (int r = 0; r < 4; ++r) {
            const int m  = mb + r;
            const float bv = bias[m];
            #pragma unroll
            for (int j = 0; j < 4; ++j) {
                const int n = n0 + wc * 64 + j * 16 + (lane & 15);
                Qp[(size_t)m * NPIX + n] = (bf16)(acc[i][j][r] + bv);
            }
        }
    }
}

// ---------------------------------------------------------------------------
// QK^T split-K partial (MFMA)  [R10-verified]
// ---------------------------------------------------------------------------
__global__ __launch_bounds__(256) void qk_partial_kernel(
    const bf16* __restrict__ qk, float* __restrict__ part)
{
    const int s  = blockIdx.x;
    const int bh = blockIdx.y;
    const int b = bh >> 3, h = bh & 7;
    const bf16* qbase = qk + ((size_t)b * QKROWS + h * HDIM) * NPIX;
    const bf16* kbase = qk + ((size_t)b * QKROWS + CH + h * HDIM) * NPIX;

    __shared__ bf16 smem[16384];

    const int t    = threadIdx.x;
    const int lane = t & 63;
    const int wave = t >> 6;

    f32x4 acc[4];
    const f32x4 zf = {0.f, 0.f, 0.f, 0.f};
    #pragma unroll
    for (int j = 0; j < 4; ++j) acc[j] = zf;

    auto STAGE = [&](int p, int n0) {
        #pragma unroll
        for (int i = 0; i < 2; ++i) {
            const int c   = t + 256 * i;
            const int row = c >> 3;
            const int nb  = ((c & 7) ^ (row & 7)) * 8;
            __builtin_amdgcn_global_load_lds(
                (const AS1 void*)(qbase + (size_t)row * NPIX + n0 + nb),
                (AS3 void*)(smem + p * 8192 + c * 8), 16, 0, 0);
            __builtin_amdgcn_global_load_lds(
                (const AS1 void*)(kbase + (size_t)row * NPIX + n0 + nb),
                (AS3 void*)(smem + p * 8192 + 4096 + c * 8), 16, 0, 0);
        }
    };

    STAGE(0, s * 256);
    __syncthreads();
    int cur = 0;

    for (int nc = 0; nc < 4; ++nc) {
        if (nc < 3) STAGE(cur ^ 1, s * 256 + (nc + 1) * 64);

        const bf16* Qs = smem + cur * 8192;
        const bf16* Ks = Qs + 4096;
        #pragma unroll
        for (int ks = 0; ks < 2; ++ks) {
            const int dr = wave * 16 + (lane & 15);
            const int ja = (ks * 4 + (lane >> 4)) ^ (dr & 7);
            const bf16x8 af = *(const bf16x8*)(Qs + dr * 64 + ja * 8);
            #pragma unroll
            for (int j = 0; j < 4; ++j) {
                const int er = j * 16 + (lane & 15);
                const int jb = (ks * 4 + (lane >> 4)) ^ (er & 7);
                const bf16x8 bf_ = *(const bf16x8*)(Ks + er * 64 + jb * 8);
                acc[j] = __builtin_amdgcn_mfma_f32_16x16x32_bf16(af, bf_, acc[j], 0, 0, 0);
            }
        }
        __syncthreads();
        cur ^= 1;
    }

    float* pb = part + (((size_t)bh * NSPLIT + s) * 64) * 64;
    #pragma unroll
    for (int j = 0; j < 4; ++j)
        #pragma unroll
        for (int r = 0; r < 4; ++r)
            pb[(size_t)(wave * 16 + (lane >> 4) * 4 + r) * 64 + j * 16 + (lane & 15)] = acc[j][r];
}

// ---------------------------------------------------------------------------
// Reduce partials + row softmax -> attn[bh][d][e] fp32  [R10-verified]
// ---------------------------------------------------------------------------
__global__ __launch_bounds__(256) void qk_reduce_softmax_kernel(
    const float* __restrict__ part, float* __restrict__ attn)
{
    const int bh = blockIdx.x;
    const int t  = threadIdx.x;
    const int r  = t >> 2;
    const int e0 = (t & 3) * 16;

    float v[16];
    #pragma unroll
    for (int i = 0; i < 16; ++i) v[i] = 0.f;

    const float* pb = part + ((size_t)bh * NSPLIT * 64) * 64 + r * 64 + e0;
    for (int s = 0; s < NSPLIT; ++s) {
        const float* ps = pb + (size_t)s * 4096;
        #pragma unroll
        for (int c4 = 0; c4 < 4; ++c4) {
            const float4 p = *(const float4*)(ps + c4 * 4);
            v[c4 * 4 + 0] += p.x; v[c4 * 4 + 1] += p.y;
            v[c4 * 4 + 2] += p.z; v[c4 * 4 + 3] += p.w;
        }
    }

    float m = -1e30f;
    #pragma unroll
    for (int i = 0; i < 16; ++i) m = fmaxf(m, v[i]);
    m = fmaxf(m, __shfl_xor(m, 1));
    m = fmaxf(m, __shfl_xor(m, 2));

    float sum = 0.f;
    #pragma unroll
    for (int i = 0; i < 16; ++i) {
        v[i] = __expf((v[i] - m) * SCALE);
        sum += v[i];
    }
    sum += __shfl_xor(sum, 1);
    sum += __shfl_xor(sum, 2);
    const float inv = 1.f / sum;

    float* arow = attn + ((size_t)bh * 64 + r) * 64 + e0;
    #pragma unroll
    for (int c4 = 0; c4 < 4; ++c4) {
        float4 o;
        o.x = v[c4 * 4 + 0] * inv; o.y = v[c4 * 4 + 1] * inv;
        o.z = v[c4 * 4 + 2] * inv; o.w = v[c4 * 4 + 3] * inv;
        *(float4*)(arow + c4 * 4) = o;
    }
}

// ---------------------------------------------------------------------------
// attn_mean[b][d][e] = mean_h attn[b][h][d][e]
// ---------------------------------------------------------------------------
__global__ __launch_bounds__(256) void attn_mean_kernel(
    const float* __restrict__ attn, float* __restrict__ om)
{
    const int idx = blockIdx.x * 256 + threadIdx.x;
    const int b = idx >> 12, de = idx & 4095;
    float s = 0.f;
    #pragma unroll
    for (int h = 0; h < 8; ++h)
        s += attn[(((size_t)b * 8 + h) << 12) + de];
    om[idx] = s * 0.125f;
}

// ---------------------------------------------------------------------------
// W'[b][o][h*64+e] = sum_d proj_w[o][h*64+d] * attn[b,h,d,e]   (fp32 -> bf16)
// ---------------------------------------------------------------------------
__global__ __launch_bounds__(256) void wprime_kernel(
    const float* __restrict__ proj_w, const float* __restrict__ attn,
    bf16* __restrict__ wp)
{
    const int o0 = blockIdx.x * 64;
    const int h  = blockIdx.y;
    const int b  = blockIdx.z;

    __shared__ float ws[64][65];
    __shared__ float as_[64][65];

    const int t = threadIdx.x;
    #pragma unroll
    for (int i = 0; i < 4; ++i) {
        const int lin = t + 256 * i;
        const int r   = lin >> 4;
        const int c4  = (lin & 15) * 4;
        const float4 wv = *(const float4*)(proj_w + (size_t)(o0 + r) * CH + h * HDIM + c4);
        ws[r][c4 + 0] = wv.x; ws[r][c4 + 1] = wv.y;
        ws[r][c4 + 2] = wv.z; ws[r][c4 + 3] = wv.w;
        const float4 av = *(const float4*)(attn + (((size_t)(b * 8 + h) * 64) + r) * 64 + c4);
        as_[r][c4 + 0] = av.x; as_[r][c4 + 1] = av.y;
        as_[r][c4 + 2] = av.z; as_[r][c4 + 3] = av.w;
    }
    __syncthreads();

    const int tx = t & 15, ty = t >> 4;
    const int to = ty * 4, te = tx * 4;
    float acc[4][4] = {};
    for (int d = 0; d < 64; ++d) {
        float a[4], bb[4];
        #pragma unroll
        for (int i = 0; i < 4; ++i) a[i]  = ws[to + i][d];
        #pragma unroll
        for (int j = 0; j < 4; ++j) bb[j] = as_[d][te + j];
        #pragma unroll
        for (int i = 0; i < 4; ++i)
            #pragma unroll
            for (int j = 0; j < 4; ++j)
                acc[i][j] = fmaf(a[i], bb[j], acc[i][j]);
    }

    bf16* wb = wp + (size_t)b * CH * CH;
    #pragma unroll
    for (int i = 0; i < 4; ++i)
        #pragma unroll
        for (int j = 0; j < 4; ++j)
            wb[(size_t)(o0 + to + i) * CH + h * HDIM + te + j] = (bf16)acc[i][j];
}

// ---------------------------------------------------------------------------
// bias2[b][o] = sum_d W'[b][o][d] * bv[d] + pb[o]   [R14-verified]
// ---------------------------------------------------------------------------
__global__ __launch_bounds__(256) void bias2_kernel(
    const bf16* __restrict__ wp, const float* __restrict__ bv,
    const float* __restrict__ pb, float* __restrict__ bias2)
{
    const int idx = blockIdx.x * 256 + threadIdx.x;   // < 4096
    const int b = idx >> 9, o = idx & 511;
    const bf16* wr = wp + ((size_t)b * CH + o) * CH;
    float s = 0.f;
    for (int d = 0; d < 512; ++d) s += (float)wr[d] * bv[d];
    bias2[idx] = s + pb[o];
}

// ---------------------------------------------------------------------------
// Generic 128x128 GEMM, K=512  [R14-verified]: Cb -> bf16 out, else fp32 Cf.
// bias indexed [b*bias_bstride + m].
// ---------------------------------------------------------------------------
__global__ __launch_bounds__(256) void gemm128_kernel(
    const bf16* __restrict__ A, const bf16* __restrict__ Bt,
    const float* __restrict__ bias, size_t bias_bstride,
    float* __restrict__ Cf, bf16* __restrict__ Cb,
    int ncols, int c_rows, size_t a_bstride, size_t bt_bstride)
{
    const int b  = blockIdx.z;
    const int m0 = blockIdx.y * 128;
    const int n0 = blockIdx.x * 128;
    const bf16* Ap = A  + (size_t)b * a_bstride;
    const bf16* Bp = Bt + (size_t)b * bt_bstride;

    __shared__ bf16 smem[16384];

    const int t    = threadIdx.x;
    const int lane = t & 63;
    const int wave = t >> 6;
    const int wr   = wave >> 1, wc = wave & 1;

    f32x4 acc[4][4];
    const f32x4 zf = {0.f, 0.f, 0.f, 0.f};
    #pragma unroll
    for (int i = 0; i < 4; ++i)
        #pragma unroll
        for (int j = 0; j < 4; ++j) acc[i][j] = zf;

    auto STAGE = [&](int p, int k0) {
        #pragma unroll
        for (int i = 0; i < 2; ++i) {
            const int c   = t + 256 * i;
            const int row = c >> 2;
            const int kb  = ((c & 3) ^ ((row >> 1) & 3)) * 8;
            __builtin_amdgcn_global_load_lds(
                (const AS1 void*)(Ap + (size_t)(m0 + row) * KDEPTH + k0 + kb),
                (AS3 void*)(smem + p * 8192 + c * 8), 16, 0, 0);
            __builtin_amdgcn_global_load_lds(
                (const AS1 void*)(Bp + (size_t)(n0 + row) * KDEPTH + k0 + kb),
                (AS3 void*)(smem + p * 8192 + 4096 + c * 8), 16, 0, 0);
        }
    };

    STAGE(0, 0);
    __syncthreads();
    int cur = 0;

    for (int kt = 0; kt < KDEPTH / 32; ++kt) {
        if (kt < KDEPTH / 32 - 1) STAGE(cur ^ 1, (kt + 1) * 32);

        const bf16* AsP = smem + cur * 8192;
        const bf16* BsP = AsP + 4096;
        bf16x8 af[4], bfv[4];
        #pragma unroll
        for (int i = 0; i < 4; ++i) {
            const int ar = wr * 64 + i * 16 + (lane & 15);
            const int ja = (lane >> 4) ^ ((ar >> 1) & 3);
            af[i]  = *(const bf16x8*)(AsP + ar * 32 + ja * 8);
            const int br = wc * 64 + i * 16 + (lane & 15);
            const int jb = (lane >> 4) ^ ((br >> 1) & 3);
            bfv[i] = *(const bf16x8*)(BsP + br * 32 + jb * 8);
        }
        #pragma unroll
        for (int i = 0; i < 4; ++i)
            #pragma unroll
            for (int j = 0; j < 4; ++j)
                acc[i][j] = __builtin_amdgcn_mfma_f32_16x16x32_bf16(
                    af[i], bfv[j], acc[i][j], 0, 0, 0);

        __syncthreads();
        cur ^= 1;
    }

    #pragma unroll
    for (int i = 0; i < 4; ++i) {
        const int mb = m0 + wr * 64 + i * 16 + (lane >> 4) * 4;
        #pragma unroll
        for (int r = 0; r < 4; ++r) {
            const int m  = mb + r;
            const float bv = bias ? bias[b * bias_bstride + m] : 0.f;
            #pragma unroll
            for (int j = 0; j < 4; ++j) {
                const int n = n0 + wc * 64 + j * 16 + (lane & 15);
                if (Cb) Cb[(size_t)b * c_rows * ncols + (size_t)m * ncols + n] =
                            (bf16)(acc[i][j][r] + bv);
                else    Cf[(size_t)b * c_rows * ncols + (size_t)m * ncols + n] =
                            acc[i][j][r] + bv;
            }
        }
    }
}

// ---------------------------------------------------------------------------
extern "C" void kernel_launch(void* const* d_in, const int* in_sizes, int n_in,
                              void* d_out, int out_size, void* d_ws, size_t ws_size,
                              hipStream_t stream)
{
    (void)in_sizes; (void)n_in; (void)out_size;
    const float* x      = (const float*)d_in[0];
    const float* qkv_w  = (const float*)d_in[1];
    const float* qkv_b  = (const float*)d_in[2];
    const float* proj_w = (const float*)d_in[3];
    const float* proj_b = (const float*)d_in[4];

    float* out       = (float*)d_out;
    float* attn_mean = out + (size_t)BATCH * CH * NPIX;

    const size_t qk_bytes   = (size_t)BATCH * QKROWS * NPIX * 2;        //  64 MiB
    const size_t xt_bytes   = (size_t)BATCH * NPIX * CH * 2;            //  32 MiB
    const size_t wq_bytes   = (size_t)OC3 * KDEPTH * 2;                 // 1.5 MiB
    const size_t attn_bytes = (size_t)BATCH * HEADS * HDIM * HDIM * 4;  //   1 MiB
    const size_t part_bytes = (size_t)BATCH * HEADS * NSPLIT * HDIM * HDIM * 4; // 16 MiB
    const size_t wp_bytes   = (size_t)BATCH * CH * CH * 2;              //   4 MiB
    const size_t wpp_bytes  = (size_t)BATCH * CH * CH * 2;              //   4 MiB
    const size_t wvt_bytes  = (size_t)CH * CH * 2;                      // 0.5 MiB
    const size_t b2_bytes   = (size_t)BATCH * CH * 4;                   //  16 KiB
    const size_t need = qk_bytes + xt_bytes + wq_bytes + attn_bytes + part_bytes +
                        wp_bytes + wpp_bytes + wvt_bytes + b2_bytes;
    if (ws_size < need) {
        fprintf(stderr, "[kernel_launch] ws_size=%zu < need=%zu — abort\n", ws_size, need);
        fflush(stderr);
        return;
    }

    char* p = (char*)d_ws;
    bf16*  qk     = (bf16*)p;             p += qk_bytes;
    bf16*  xt     = (bf16*)p;             p += xt_bytes;
    bf16*  wq_b   = (bf16*)p;             p += wq_bytes;
    float* attn   = (float*)p;            p += attn_bytes;
    float* part   = (float*)p;            p += part_bytes;
    bf16*  wprime = (bf16*)p;             p += wp_bytes;
    bf16*  wpp    = (bf16*)p;             p += wpp_bytes;
    bf16*  wvt    = (bf16*)p;             p += wvt_bytes;
    float* bias2  = (float*)p;

    // 0) weight convert + Wv transpose
    convert_bf16_kernel<<<dim3((OC3 * KDEPTH + 255) / 256), 256, 0, stream>>>(
        qkv_w, wq_b, OC3 * KDEPTH);
    wvt_kernel<<<dim3(8, 8), 256, 0, stream>>>(wq_b + (size_t)2 * CH * KDEPTH, wvt);

    // 1) x -> xt (transpose + bf16)
    transpose_convert_kernel<<<dim3(NPIX / 64, CH / 64, BATCH), 256, 0, stream>>>(x, xt);

    // 2) Q,K GEMM -> bf16 qk[b][1024][4096] (c-major)
    gemm_qk_kernel<<<dim3(NPIX / 128, QKROWS / 128, BATCH), 256, 0, stream>>>(
        wq_b, xt, qkv_b, qk);

    // 3) QK^T split-K (MFMA) + softmax
    qk_partial_kernel<<<dim3(NSPLIT, BATCH * HEADS), 256, 0, stream>>>(qk, part);
    qk_reduce_softmax_kernel<<<dim3(BATCH * HEADS), 256, 0, stream>>>(part, attn);

    // 4) attn mean over heads (output 1)
    attn_mean_kernel<<<dim3(BATCH * HDIM * HDIM / 256), 256, 0, stream>>>(attn, attn_mean);

    // 5) W' = proj_w · blockdiag(attn)
    wprime_kernel<<<dim3(CH / 64, HEADS, BATCH), 256, 0, stream>>>(proj_w, attn, wprime);

    // 6) W'' = W' · Wv (bf16) ; bias'' = W'·bv + pb
    gemm128_kernel<<<dim3(CH / 128, CH / 128, BATCH), 256, 0, stream>>>(
        wprime, wvt, nullptr, 0, nullptr, wpp, CH, CH, (size_t)CH * CH, 0);
    bias2_kernel<<<dim3(BATCH * CH / 256), 256, 0, stream>>>(
        wprime, qkv_b + 2 * CH, proj_b, bias2);

    // 7) out = W''_b · x + bias''
    gemm128_kernel<<<dim3(NPIX / 128, CH / 128, BATCH), 256, 0, stream>>>(
        wpp, xt, bias2, CH, out, nullptr, NPIX, CH, (size_t)CH * CH,
        (size_t)NPIX * KDEPTH);
}

// Round 16
// 162.366 us; speedup vs baseline: 1.1651x; 1.0344x over previous
//
#include <hip/hip_runtime.h>
#include <cstdio>
#include <cstdint>

// Problem constants
#define BATCH 8
#define CH    512
#define OC3   1536      // 3*CH
#define QKROWS 1024     // Q+K channel rows (bf16)
#define NPIX  4096      // 64*64
#define HEADS 8
#define HDIM  64
#define KDEPTH 512
#define SCALE 0.125f    // 64^-0.5
#define NSPLIT 8        // split-K factor for QK^T (512 n per split)

typedef __bf16 bf16;
typedef __bf16 bf16x4 __attribute__((ext_vector_type(4)));
typedef __bf16 bf16x8 __attribute__((ext_vector_type(8)));
typedef float  f32x4  __attribute__((ext_vector_type(4)));

#define AS1 __attribute__((address_space(1)))
#define AS3 __attribute__((address_space(3)))

// ---------------------------------------------------------------------------
// fp32 -> bf16 flat convert (weights)
// ---------------------------------------------------------------------------
__global__ __launch_bounds__(256) void convert_bf16_kernel(
    const float* __restrict__ in, bf16* __restrict__ out, int n)
{
    const int i = blockIdx.x * 256 + threadIdx.x;
    if (i < n) out[i] = (bf16)in[i];
}

// ---------------------------------------------------------------------------
// Wv [d][c] bf16 -> wvt [c][d] bf16  (512x512 transpose)
// ---------------------------------------------------------------------------
__global__ __launch_bounds__(256) void wvt_kernel(
    const bf16* __restrict__ wv, bf16* __restrict__ wvt)
{
    const int c0 = blockIdx.x * 64;
    const int d0 = blockIdx.y * 64;
    __shared__ bf16 tl[64][72];
    const int t = threadIdx.x;

    #pragma unroll
    for (int i = 0; i < 2; ++i) {
        const int lin = t + 256 * i;
        const int row = lin >> 3;
        const int c8  = (lin & 7) * 8;
        *(bf16x8*)&tl[row][c8] = *(const bf16x8*)(wv + (size_t)(d0 + row) * CH + c0 + c8);
    }
    __syncthreads();
    #pragma unroll
    for (int i = 0; i < 2; ++i) {
        const int lin  = t + 256 * i;
        const int crow = lin >> 3;
        const int d8   = (lin & 7) * 8;
        bf16x8 v;
        #pragma unroll
        for (int j = 0; j < 8; ++j) v[j] = tl[d8 + j][crow];
        *(bf16x8*)(wvt + (size_t)(c0 + crow) * CH + d0 + d8) = v;
    }
}

// ---------------------------------------------------------------------------
// x [b][512][4096] fp32 -> xt [b][4096][512] bf16 (transpose)
// ---------------------------------------------------------------------------
__global__ __launch_bounds__(256) void transpose_convert_kernel(
    const float* __restrict__ src, bf16* __restrict__ dst)
{
    const int b  = blockIdx.z;
    const int n0 = blockIdx.x * 64;
    const int c0 = blockIdx.y * 64;
    __shared__ float tile[64][65];
    const int t = threadIdx.x;
    const float* xp = src + (size_t)b * CH * NPIX;

    #pragma unroll
    for (int i = 0; i < 4; ++i) {
        const int lin = t + 256 * i;
        const int r   = lin >> 4;
        const int c4  = (lin & 15) * 4;
        const float4 v = *(const float4*)(xp + (size_t)(c0 + r) * 4096 + n0 + c4);
        tile[r][c4 + 0] = v.x; tile[r][c4 + 1] = v.y;
        tile[r][c4 + 2] = v.z; tile[r][c4 + 3] = v.w;
    }
    __syncthreads();

    bf16* op = dst + (size_t)b * NPIX * CH;
    #pragma unroll
    for (int i = 0; i < 2; ++i) {
        const int lin = t + 256 * i;
        const int n   = lin >> 3;
        const int c8  = (lin & 7) * 8;
        bf16x8 v;
        #pragma unroll
        for (int jj = 0; jj < 8; ++jj) v[jj] = (bf16)tile[c8 + jj][n];
        *(bf16x8*)(op + (size_t)(n0 + n) * CH + c0 + c8) = v;
    }
}

// ---------------------------------------------------------------------------
// QK GEMM: qk[b][m][n] bf16 = sum_k Wqk[m][k]*xt[b][n][k] + bias[m]
// 128x128 tile, BK=32, 2-phase dbuf + chunk XOR swizzle.
// R16: XCD-swizzled blockIdx (group B-panel sharers per XCD) +
//      LDS-bounce coalesced bf16 epilogue (int4 row writes).
// ---------------------------------------------------------------------------
__global__ __launch_bounds__(256) void gemm_qk_kernel(
    const bf16* __restrict__ A, const bf16* __restrict__ Bt,
    const float* __restrict__ bias, bf16* __restrict__ qkb)
{
    // bijective XCD swizzle: logical id = by + gridDim.y * bx, y fastest
    const int nwg  = gridDim.x * gridDim.y;          // 256 (divisible by 8)
    const int orig = blockIdx.x + gridDim.x * blockIdx.y;
    const int wg   = (orig & 7) * (nwg >> 3) + (orig >> 3);
    const int by   = wg % gridDim.y;
    const int bx   = wg / gridDim.y;

    const int b  = blockIdx.z;
    const int m0 = by * 128;
    const int n0 = bx * 128;
    const bf16* Ap = A;
    const bf16* Bp = Bt + (size_t)b * NPIX * KDEPTH;

    __shared__ bf16 smem[16384];

    const int t    = threadIdx.x;
    const int lane = t & 63;
    const int wave = t >> 6;
    const int wr   = wave >> 1, wc = wave & 1;

    f32x4 acc[4][4];
    const f32x4 zf = {0.f, 0.f, 0.f, 0.f};
    #pragma unroll
    for (int i = 0; i < 4; ++i)
        #pragma unroll
        for (int j = 0; j < 4; ++j) acc[i][j] = zf;

    auto STAGE = [&](int p, int k0) {
        #pragma unroll
        for (int i = 0; i < 2; ++i) {
            const int c   = t + 256 * i;
            const int row = c >> 2;
            const int kb  = ((c & 3) ^ ((row >> 1) & 3)) * 8;
            __builtin_amdgcn_global_load_lds(
                (const AS1 void*)(Ap + (size_t)(m0 + row) * KDEPTH + k0 + kb),
                (AS3 void*)(smem + p * 8192 + c * 8), 16, 0, 0);
            __builtin_amdgcn_global_load_lds(
                (const AS1 void*)(Bp + (size_t)(n0 + row) * KDEPTH + k0 + kb),
                (AS3 void*)(smem + p * 8192 + 4096 + c * 8), 16, 0, 0);
        }
    };

    STAGE(0, 0);
    __syncthreads();
    int cur = 0;

    for (int kt = 0; kt < KDEPTH / 32; ++kt) {
        if (kt < KDEPTH / 32 - 1) STAGE(cur ^ 1, (kt + 1) * 32);

        const bf16* AsP = smem + cur * 8192;
        const bf16* BsP = AsP + 4096;
        bf16x8 af[4], bfv[4];
        #pragma unroll
        for (int i = 0; i < 4; ++i) {
            const int ar = wr * 64 + i * 16 + (lane & 15);
            const int ja = (lane >> 4) ^ ((ar >> 1) & 3);
            af[i]  = *(const bf16x8*)(AsP + ar * 32 + ja * 8);
            const int br = wc * 64 + i * 16 + (lane & 15);
            const int jb = (lane >> 4) ^ ((br >> 1) & 3);
            bfv[i] = *(const bf16x8*)(BsP + br * 32 + jb * 8);
        }
        #pragma unroll
        for (int i = 0; i < 4; ++i)
            #pragma unroll
            for (int j = 0; j < 4; ++j)
                acc[i][j] = __builtin_amdgcn_mfma_f32_16x16x32_bf16(
                    af[i], bfv[j], acc[i][j], 0, 0, 0);

        __syncthreads();
        cur ^= 1;
    }

    // LDS-bounce coalesced epilogue: C-tile 128x128 bf16 = 32 KB = smem exactly
    {
        bf16* ct = smem;   // dead after final loop barrier
        #pragma unroll
        for (int i = 0; i < 4; ++i) {
            const int ml = wr * 64 + i * 16 + (lane >> 4) * 4;
            #pragma unroll
            for (int r = 0; r < 4; ++r) {
                const float bv = bias[m0 + ml + r];
                #pragma unroll
                for (int j = 0; j < 4; ++j) {
                    const int n = wc * 64 + j * 16 + (lane & 15);
                    ct[(ml + r) * 128 + n] = (bf16)(acc[i][j][r] + bv);
                }
            }
        }
        __syncthreads();
        bf16* Qp = qkb + (size_t)b * QKROWS * NPIX;
        #pragma unroll
        for (int ii = 0; ii < 8; ++ii) {
            const int c   = t + 256 * ii;   // 0..2047 int4 chunks
            const int row = c >> 4;
            const int seg = c & 15;
            const int4 v = *(const int4*)(ct + row * 128 + seg * 8);
            *(int4*)(Qp + (size_t)(m0 + row) * NPIX + n0 + seg * 8) = v;
        }
    }
}

// ---------------------------------------------------------------------------
// QK^T split-K partial (MFMA): NSPLIT=8, 512 n per split.
// ---------------------------------------------------------------------------
__global__ __launch_bounds__(256) void qk_partial_kernel(
    const bf16* __restrict__ qk, float* __restrict__ part)
{
    const int s  = blockIdx.x;
    const int bh = blockIdx.y;
    const int b = bh >> 3, h = bh & 7;
    const bf16* qbase = qk + ((size_t)b * QKROWS + h * HDIM) * NPIX;
    const bf16* kbase = qk + ((size_t)b * QKROWS + CH + h * HDIM) * NPIX;

    __shared__ bf16 smem[16384];

    const int t    = threadIdx.x;
    const int lane = t & 63;
    const int wave = t >> 6;

    f32x4 acc[4];
    const f32x4 zf = {0.f, 0.f, 0.f, 0.f};
    #pragma unroll
    for (int j = 0; j < 4; ++j) acc[j] = zf;

    auto STAGE = [&](int p, int n0) {
        #pragma unroll
        for (int i = 0; i < 2; ++i) {
            const int c   = t + 256 * i;
            const int row = c >> 3;
            const int nb  = ((c & 7) ^ (row & 7)) * 8;
            __builtin_amdgcn_global_load_lds(
                (const AS1 void*)(qbase + (size_t)row * NPIX + n0 + nb),
                (AS3 void*)(smem + p * 8192 + c * 8), 16, 0, 0);
            __builtin_amdgcn_global_load_lds(
                (const AS1 void*)(kbase + (size_t)row * NPIX + n0 + nb),
                (AS3 void*)(smem + p * 8192 + 4096 + c * 8), 16, 0, 0);
        }
    };

    STAGE(0, s * 512);
    __syncthreads();
    int cur = 0;

    for (int nc = 0; nc < 8; ++nc) {
        if (nc < 7) STAGE(cur ^ 1, s * 512 + (nc + 1) * 64);

        const bf16* Qs = smem + cur * 8192;
        const bf16* Ks = Qs + 4096;
        #pragma unroll
        for (int ks = 0; ks < 2; ++ks) {
            const int dr = wave * 16 + (lane & 15);
            const int ja = (ks * 4 + (lane >> 4)) ^ (dr & 7);
            const bf16x8 af = *(const bf16x8*)(Qs + dr * 64 + ja * 8);
            #pragma unroll
            for (int j = 0; j < 4; ++j) {
                const int er = j * 16 + (lane & 15);
                const int jb = (ks * 4 + (lane >> 4)) ^ (er & 7);
                const bf16x8 bf_ = *(const bf16x8*)(Ks + er * 64 + jb * 8);
                acc[j] = __builtin_amdgcn_mfma_f32_16x16x32_bf16(af, bf_, acc[j], 0, 0, 0);
            }
        }
        __syncthreads();
        cur ^= 1;
    }

    float* pb = part + (((size_t)bh * NSPLIT + s) * 64) * 64;
    #pragma unroll
    for (int j = 0; j < 4; ++j)
        #pragma unroll
        for (int r = 0; r < 4; ++r)
            pb[(size_t)(wave * 16 + (lane >> 4) * 4 + r) * 64 + j * 16 + (lane & 15)] = acc[j][r];
}

// ---------------------------------------------------------------------------
// Reduce partials + row softmax -> attn[bh][d][e] fp32
// ---------------------------------------------------------------------------
__global__ __launch_bounds__(256) void qk_reduce_softmax_kernel(
    const float* __restrict__ part, float* __restrict__ attn)
{
    const int bh = blockIdx.x;
    const int t  = threadIdx.x;
    const int r  = t >> 2;
    const int e0 = (t & 3) * 16;

    float v[16];
    #pragma unroll
    for (int i = 0; i < 16; ++i) v[i] = 0.f;

    const float* pb = part + ((size_t)bh * NSPLIT * 64) * 64 + r * 64 + e0;
    for (int s = 0; s < NSPLIT; ++s) {
        const float* ps = pb + (size_t)s * 4096;
        #pragma unroll
        for (int c4 = 0; c4 < 4; ++c4) {
            const float4 p = *(const float4*)(ps + c4 * 4);
            v[c4 * 4 + 0] += p.x; v[c4 * 4 + 1] += p.y;
            v[c4 * 4 + 2] += p.z; v[c4 * 4 + 3] += p.w;
        }
    }

    float m = -1e30f;
    #pragma unroll
    for (int i = 0; i < 16; ++i) m = fmaxf(m, v[i]);
    m = fmaxf(m, __shfl_xor(m, 1));
    m = fmaxf(m, __shfl_xor(m, 2));

    float sum = 0.f;
    #pragma unroll
    for (int i = 0; i < 16; ++i) {
        v[i] = __expf((v[i] - m) * SCALE);
        sum += v[i];
    }
    sum += __shfl_xor(sum, 1);
    sum += __shfl_xor(sum, 2);
    const float inv = 1.f / sum;

    float* arow = attn + ((size_t)bh * 64 + r) * 64 + e0;
    #pragma unroll
    for (int c4 = 0; c4 < 4; ++c4) {
        float4 o;
        o.x = v[c4 * 4 + 0] * inv; o.y = v[c4 * 4 + 1] * inv;
        o.z = v[c4 * 4 + 2] * inv; o.w = v[c4 * 4 + 3] * inv;
        *(float4*)(arow + c4 * 4) = o;
    }
}

// ---------------------------------------------------------------------------
// attn_mean[b][d][e] = mean_h attn[b][h][d][e]
// ---------------------------------------------------------------------------
__global__ __launch_bounds__(256) void attn_mean_kernel(
    const float* __restrict__ attn, float* __restrict__ om)
{
    const int idx = blockIdx.x * 256 + threadIdx.x;
    const int b = idx >> 12, de = idx & 4095;
    float s = 0.f;
    #pragma unroll
    for (int h = 0; h < 8; ++h)
        s += attn[(((size_t)b * 8 + h) << 12) + de];
    om[idx] = s * 0.125f;
}

// ---------------------------------------------------------------------------
// W'[b][o][h*64+e] = sum_d proj_w[o][h*64+d] * attn[b,h,d,e]   (fp32 -> bf16)
// ---------------------------------------------------------------------------
__global__ __launch_bounds__(256) void wprime_kernel(
    const float* __restrict__ proj_w, const float* __restrict__ attn,
    bf16* __restrict__ wp)
{
    const int o0 = blockIdx.x * 64;
    const int h  = blockIdx.y;
    const int b  = blockIdx.z;

    __shared__ float ws[64][65];
    __shared__ float as_[64][65];

    const int t = threadIdx.x;
    #pragma unroll
    for (int i = 0; i < 4; ++i) {
        const int lin = t + 256 * i;
        const int r   = lin >> 4;
        const int c4  = (lin & 15) * 4;
        const float4 wv = *(const float4*)(proj_w + (size_t)(o0 + r) * CH + h * HDIM + c4);
        ws[r][c4 + 0] = wv.x; ws[r][c4 + 1] = wv.y;
        ws[r][c4 + 2] = wv.z; ws[r][c4 + 3] = wv.w;
        const float4 av = *(const float4*)(attn + (((size_t)(b * 8 + h) * 64) + r) * 64 + c4);
        as_[r][c4 + 0] = av.x; as_[r][c4 + 1] = av.y;
        as_[r][c4 + 2] = av.z; as_[r][c4 + 3] = av.w;
    }
    __syncthreads();

    const int tx = t & 15, ty = t >> 4;
    const int to = ty * 4, te = tx * 4;
    float acc[4][4] = {};
    for (int d = 0; d < 64; ++d) {
        float a[4], bb[4];
        #pragma unroll
        for (int i = 0; i < 4; ++i) a[i]  = ws[to + i][d];
        #pragma unroll
        for (int j = 0; j < 4; ++j) bb[j] = as_[d][te + j];
        #pragma unroll
        for (int i = 0; i < 4; ++i)
            #pragma unroll
            for (int j = 0; j < 4; ++j)
                acc[i][j] = fmaf(a[i], bb[j], acc[i][j]);
    }

    bf16* wb = wp + (size_t)b * CH * CH;
    #pragma unroll
    for (int i = 0; i < 4; ++i)
        #pragma unroll
        for (int j = 0; j < 4; ++j)
            wb[(size_t)(o0 + to + i) * CH + h * HDIM + te + j] = (bf16)acc[i][j];
}

// ---------------------------------------------------------------------------
// bias2[b][o] = sum_d W'[b][o][d] * bv[d] + pb[o]
// ---------------------------------------------------------------------------
__global__ __launch_bounds__(256) void bias2_kernel(
    const bf16* __restrict__ wp, const float* __restrict__ bv,
    const float* __restrict__ pb, float* __restrict__ bias2)
{
    const int idx = blockIdx.x * 256 + threadIdx.x;   // < 4096
    const int b = idx >> 9, o = idx & 511;
    const bf16* wr = wp + ((size_t)b * CH + o) * CH;
    float s = 0.f;
    for (int d = 0; d < 512; ++d) s += (float)wr[d] * bv[d];
    bias2[idx] = s + pb[o];
}

// ---------------------------------------------------------------------------
// Generic 128x128 GEMM, K=512: Cb -> bf16 out (scalar epilogue, small use),
// else fp32 Cf via LDS-bounce coalesced epilogue. XCD-swizzled blockIdx.
// bias indexed [b*bias_bstride + m].
// ---------------------------------------------------------------------------
__global__ __launch_bounds__(256) void gemm128_kernel(
    const bf16* __restrict__ A, const bf16* __restrict__ Bt,
    const float* __restrict__ bias, size_t bias_bstride,
    float* __restrict__ Cf, bf16* __restrict__ Cb,
    int ncols, int c_rows, size_t a_bstride, size_t bt_bstride)
{
    // bijective XCD swizzle (nwg divisible by 8 in all uses: 128, 16)
    const int nwg  = gridDim.x * gridDim.y;
    const int orig = blockIdx.x + gridDim.x * blockIdx.y;
    const int wg   = (orig & 7) * (nwg >> 3) + (orig >> 3);
    const int by   = wg % gridDim.y;
    const int bx   = wg / gridDim.y;

    const int b  = blockIdx.z;
    const int m0 = by * 128;
    const int n0 = bx * 128;
    const bf16* Ap = A  + (size_t)b * a_bstride;
    const bf16* Bp = Bt + (size_t)b * bt_bstride;

    __shared__ bf16 smem[16384];

    const int t    = threadIdx.x;
    const int lane = t & 63;
    const int wave = t >> 6;
    const int wr   = wave >> 1, wc = wave & 1;

    f32x4 acc[4][4];
    const f32x4 zf = {0.f, 0.f, 0.f, 0.f};
    #pragma unroll
    for (int i = 0; i < 4; ++i)
        #pragma unroll
        for (int j = 0; j < 4; ++j) acc[i][j] = zf;

    auto STAGE = [&](int p, int k0) {
        #pragma unroll
        for (int i = 0; i < 2; ++i) {
            const int c   = t + 256 * i;
            const int row = c >> 2;
            const int kb  = ((c & 3) ^ ((row >> 1) & 3)) * 8;
            __builtin_amdgcn_global_load_lds(
                (const AS1 void*)(Ap + (size_t)(m0 + row) * KDEPTH + k0 + kb),
                (AS3 void*)(smem + p * 8192 + c * 8), 16, 0, 0);
            __builtin_amdgcn_global_load_lds(
                (const AS1 void*)(Bp + (size_t)(n0 + row) * KDEPTH + k0 + kb),
                (AS3 void*)(smem + p * 8192 + 4096 + c * 8), 16, 0, 0);
        }
    };

    STAGE(0, 0);
    __syncthreads();
    int cur = 0;

    for (int kt = 0; kt < KDEPTH / 32; ++kt) {
        if (kt < KDEPTH / 32 - 1) STAGE(cur ^ 1, (kt + 1) * 32);

        const bf16* AsP = smem + cur * 8192;
        const bf16* BsP = AsP + 4096;
        bf16x8 af[4], bfv[4];
        #pragma unroll
        for (int i = 0; i < 4; ++i) {
            const int ar = wr * 64 + i * 16 + (lane & 15);
            const int ja = (lane >> 4) ^ ((ar >> 1) & 3);
            af[i]  = *(const bf16x8*)(AsP + ar * 32 + ja * 8);
            const int br = wc * 64 + i * 16 + (lane & 15);
            const int jb = (lane >> 4) ^ ((br >> 1) & 3);
            bfv[i] = *(const bf16x8*)(BsP + br * 32 + jb * 8);
        }
        #pragma unroll
        for (int i = 0; i < 4; ++i)
            #pragma unroll
            for (int j = 0; j < 4; ++j)
                acc[i][j] = __builtin_amdgcn_mfma_f32_16x16x32_bf16(
                    af[i], bfv[j], acc[i][j], 0, 0, 0);

        __syncthreads();
        cur ^= 1;
    }

    if (Cb) {
        // small bf16 output path (W'' GEMM): scalar stores, negligible traffic
        #pragma unroll
        for (int i = 0; i < 4; ++i) {
            const int mb = m0 + wr * 64 + i * 16 + (lane >> 4) * 4;
            #pragma unroll
            for (int r = 0; r < 4; ++r) {
                const int m  = mb + r;
                const float bv = bias ? bias[b * bias_bstride + m] : 0.f;
                #pragma unroll
                for (int j = 0; j < 4; ++j) {
                    const int n = n0 + wc * 64 + j * 16 + (lane & 15);
                    Cb[(size_t)b * c_rows * ncols + (size_t)m * ncols + n] =
                        (bf16)(acc[i][j][r] + bv);
                }
            }
        }
    } else {
        // fp32 output: LDS-bounce in two 128x64 halves (32 KB each)
        float* ct = (float*)smem;
        float* Cp = Cf + (size_t)b * c_rows * ncols;
        #pragma unroll
        for (int p = 0; p < 2; ++p) {
            if (wc == p) {
                #pragma unroll
                for (int i = 0; i < 4; ++i) {
                    const int ml = wr * 64 + i * 16 + (lane >> 4) * 4;
                    #pragma unroll
                    for (int r = 0; r < 4; ++r) {
                        const float bv = bias ? bias[b * bias_bstride + m0 + ml + r] : 0.f;
                        #pragma unroll
                        for (int j = 0; j < 4; ++j) {
                            const int n = j * 16 + (lane & 15);
                            ct[(ml + r) * 64 + n] = acc[i][j][r] + bv;
                        }
                    }
                }
            }
            __syncthreads();
            #pragma unroll
            for (int ii = 0; ii < 8; ++ii) {
                const int c   = t + 256 * ii;   // 0..2047 float4 chunks
                const int row = c >> 4;
                const int seg = c & 15;
                const float4 v = *(const float4*)(ct + row * 64 + seg * 4);
                *(float4*)(Cp + (size_t)(m0 + row) * ncols + n0 + p * 64 + seg * 4) = v;
            }
            __syncthreads();
        }
    }
}

// ---------------------------------------------------------------------------
extern "C" void kernel_launch(void* const* d_in, const int* in_sizes, int n_in,
                              void* d_out, int out_size, void* d_ws, size_t ws_size,
                              hipStream_t stream)
{
    (void)in_sizes; (void)n_in; (void)out_size;
    const float* x      = (const float*)d_in[0];
    const float* qkv_w  = (const float*)d_in[1];
    const float* qkv_b  = (const float*)d_in[2];
    const float* proj_w = (const float*)d_in[3];
    const float* proj_b = (const float*)d_in[4];

    float* out       = (float*)d_out;
    float* attn_mean = out + (size_t)BATCH * CH * NPIX;

    const size_t qk_bytes   = (size_t)BATCH * QKROWS * NPIX * 2;        //  64 MiB
    const size_t xt_bytes   = (size_t)BATCH * NPIX * CH * 2;            //  32 MiB
    const size_t wq_bytes   = (size_t)OC3 * KDEPTH * 2;                 // 1.5 MiB
    const size_t attn_bytes = (size_t)BATCH * HEADS * HDIM * HDIM * 4;  //   1 MiB
    const size_t part_bytes = (size_t)BATCH * HEADS * NSPLIT * HDIM * HDIM * 4; // 8 MiB
    const size_t wp_bytes   = (size_t)BATCH * CH * CH * 2;              //   4 MiB
    const size_t wpp_bytes  = (size_t)BATCH * CH * CH * 2;              //   4 MiB
    const size_t wvt_bytes  = (size_t)CH * CH * 2;                      // 0.5 MiB
    const size_t b2_bytes   = (size_t)BATCH * CH * 4;                   //  16 KiB
    const size_t need = qk_bytes + xt_bytes + wq_bytes + attn_bytes + part_bytes +
                        wp_bytes + wpp_bytes + wvt_bytes + b2_bytes;
    if (ws_size < need) {
        fprintf(stderr, "[kernel_launch] ws_size=%zu < need=%zu — abort\n", ws_size, need);
        fflush(stderr);
        return;
    }

    char* p = (char*)d_ws;
    bf16*  qk     = (bf16*)p;             p += qk_bytes;
    bf16*  xt     = (bf16*)p;             p += xt_bytes;
    bf16*  wq_b   = (bf16*)p;             p += wq_bytes;
    float* attn   = (float*)p;            p += attn_bytes;
    float* part   = (float*)p;            p += part_bytes;
    bf16*  wprime = (bf16*)p;             p += wp_bytes;
    bf16*  wpp    = (bf16*)p;             p += wpp_bytes;
    bf16*  wvt    = (bf16*)p;             p += wvt_bytes;
    float* bias2  = (float*)p;

    // 0) weight convert + Wv transpose
    convert_bf16_kernel<<<dim3((OC3 * KDEPTH + 255) / 256), 256, 0, stream>>>(
        qkv_w, wq_b, OC3 * KDEPTH);
    wvt_kernel<<<dim3(8, 8), 256, 0, stream>>>(wq_b + (size_t)2 * CH * KDEPTH, wvt);

    // 1) x -> xt (transpose + bf16)
    transpose_convert_kernel<<<dim3(NPIX / 64, CH / 64, BATCH), 256, 0, stream>>>(x, xt);

    // 2) Q,K GEMM -> bf16 qk[b][1024][4096] (c-major)
    gemm_qk_kernel<<<dim3(NPIX / 128, QKROWS / 128, BATCH), 256, 0, stream>>>(
        wq_b, xt, qkv_b, qk);

    // 3) QK^T split-K (MFMA) + softmax
    qk_partial_kernel<<<dim3(NSPLIT, BATCH * HEADS), 256, 0, stream>>>(qk, part);
    qk_reduce_softmax_kernel<<<dim3(BATCH * HEADS), 256, 0, stream>>>(part, attn);

    // 4) attn mean over heads (output 1)
    attn_mean_kernel<<<dim3(BATCH * HDIM * HDIM / 256), 256, 0, stream>>>(attn, attn_mean);

    // 5) W' = proj_w · blockdiag(attn)
    wprime_kernel<<<dim3(CH / 64, HEADS, BATCH), 256, 0, stream>>>(proj_w, attn, wprime);

    // 6) W'' = W' · Wv (bf16) ; bias'' = W'·bv + pb
    gemm128_kernel<<<dim3(CH / 128, CH / 128, BATCH), 256, 0, stream>>>(
        wprime, wvt, nullptr, 0, nullptr, wpp, CH, CH, (size_t)CH * CH, 0);
    bias2_kernel<<<dim3(BATCH * CH / 256), 256, 0, stream>>>(
        wprime, qkv_b + 2 * CH, proj_b, bias2);

    // 7) out = W''_b · x + bias''  (fp32 coalesced epilogue)
    gemm128_kernel<<<dim3(NPIX / 128, CH / 128, BATCH), 256, 0, stream>>>(
        wpp, xt, bias2, CH, out, nullptr, NPIX, CH, (size_t)CH * CH,
        (size_t)NPIX * KDEPTH);
}

// Round 17
// 151.294 us; speedup vs baseline: 1.2504x; 1.0732x over previous
//
#include <hip/hip_runtime.h>
#include <cstdio>
#include <cstdint>

// Problem constants
#define BATCH 8
#define CH    512
#define OC3   1536      // 3*CH
#define QKROWS 1024     // Q+K channel rows (bf16)
#define NPIX  4096      // 64*64
#define HEADS 8
#define HDIM  64
#define KDEPTH 512
#define SCALE 0.125f    // 64^-0.5
#define NSPLIT 8        // split-K factor for QK^T (512 n per split)

typedef __bf16 bf16;
typedef __bf16 bf16x4 __attribute__((ext_vector_type(4)));
typedef __bf16 bf16x8 __attribute__((ext_vector_type(8)));
typedef float  f32x4  __attribute__((ext_vector_type(4)));

#define AS1 __attribute__((address_space(1)))
#define AS3 __attribute__((address_space(3)))

// ---------------------------------------------------------------------------
// Merged: fp32 -> bf16 flat convert of qkv_w (blocks 0..3071)  +
//         Wv^T build: wvt[c][d] = qkv_w[1024+d][c] bf16 (blocks 3072..3135)
// ---------------------------------------------------------------------------
__global__ __launch_bounds__(256) void convert_wvt_kernel(
    const float* __restrict__ qkv_w, bf16* __restrict__ wq_b,
    bf16* __restrict__ wvt)
{
    const int bid = blockIdx.x;
    const int t = threadIdx.x;
    if (bid < (OC3 * KDEPTH) / 256) {
        const int i = bid * 256 + t;
        wq_b[i] = (bf16)qkv_w[i];
        return;
    }
    // Wv transpose tile (from fp32 source; independent of the convert)
    const int tb = bid - (OC3 * KDEPTH) / 256;   // 0..63
    const int c0 = (tb & 7) * 64;
    const int d0 = (tb >> 3) * 64;
    __shared__ float tl[64][68];
    const float* wv = qkv_w + (size_t)2 * CH * KDEPTH;
    #pragma unroll
    for (int i = 0; i < 4; ++i) {
        const int lin = t + 256 * i;     // 0..1023
        const int row = lin >> 4;        // d-local
        const int c4  = (lin & 15) * 4;
        const float4 v = *(const float4*)(wv + (size_t)(d0 + row) * CH + c0 + c4);
        tl[row][c4 + 0] = v.x; tl[row][c4 + 1] = v.y;
        tl[row][c4 + 2] = v.z; tl[row][c4 + 3] = v.w;
    }
    __syncthreads();
    #pragma unroll
    for (int i = 0; i < 2; ++i) {
        const int lin  = t + 256 * i;    // 0..511
        const int crow = lin >> 3;       // c-local
        const int d8   = (lin & 7) * 8;
        bf16x8 v;
        #pragma unroll
        for (int j = 0; j < 8; ++j) v[j] = (bf16)tl[d8 + j][crow];
        *(bf16x8*)(wvt + (size_t)(c0 + crow) * CH + d0 + d8) = v;
    }
}

// ---------------------------------------------------------------------------
// x [b][512][4096] fp32 -> xt [b][4096][512] bf16 (transpose)
// ---------------------------------------------------------------------------
__global__ __launch_bounds__(256) void transpose_convert_kernel(
    const float* __restrict__ src, bf16* __restrict__ dst)
{
    const int b  = blockIdx.z;
    const int n0 = blockIdx.x * 64;
    const int c0 = blockIdx.y * 64;
    __shared__ float tile[64][65];
    const int t = threadIdx.x;
    const float* xp = src + (size_t)b * CH * NPIX;

    #pragma unroll
    for (int i = 0; i < 4; ++i) {
        const int lin = t + 256 * i;
        const int r   = lin >> 4;
        const int c4  = (lin & 15) * 4;
        const float4 v = *(const float4*)(xp + (size_t)(c0 + r) * 4096 + n0 + c4);
        tile[r][c4 + 0] = v.x; tile[r][c4 + 1] = v.y;
        tile[r][c4 + 2] = v.z; tile[r][c4 + 3] = v.w;
    }
    __syncthreads();

    bf16* op = dst + (size_t)b * NPIX * CH;
    #pragma unroll
    for (int i = 0; i < 2; ++i) {
        const int lin = t + 256 * i;
        const int n   = lin >> 3;
        const int c8  = (lin & 7) * 8;
        bf16x8 v;
        #pragma unroll
        for (int jj = 0; jj < 8; ++jj) v[jj] = (bf16)tile[c8 + jj][n];
        *(bf16x8*)(op + (size_t)(n0 + n) * CH + c0 + c8) = v;
    }
}

// ---------------------------------------------------------------------------
// QK GEMM: qk[b][m][n] bf16 = sum_k Wqk[m][k]*xt[b][n][k] + bias[m]
// R17: 3-buffer LDS ring, 2-deep prefetch, raw s_barrier + counted
// vmcnt(4) (never 0 mid-loop -> loads stay in flight across barriers, T4),
// setprio around MFMA (T5). XCD swizzle + coalesced bf16 epilogue kept.
// ---------------------------------------------------------------------------
__global__ __launch_bounds__(256) void gemm_qk_kernel(
    const bf16* __restrict__ A, const bf16* __restrict__ Bt,
    const float* __restrict__ bias, bf16* __restrict__ qkb)
{
    const int nwg  = gridDim.x * gridDim.y;          // 256
    const int orig = blockIdx.x + gridDim.x * blockIdx.y;
    const int wg   = (orig & 7) * (nwg >> 3) + (orig >> 3);
    const int by   = wg % gridDim.y;
    const int bx   = wg / gridDim.y;

    const int b  = blockIdx.z;
    const int m0 = by * 128;
    const int n0 = bx * 128;
    const bf16* Ap = A;
    const bf16* Bp = Bt + (size_t)b * NPIX * KDEPTH;

    __shared__ bf16 smem[3 * 8192];   // ring of 3 K-tile buffers (48 KB)

    const int t    = threadIdx.x;
    const int lane = t & 63;
    const int wave = t >> 6;
    const int wr   = wave >> 1, wc = wave & 1;

    f32x4 acc[4][4];
    const f32x4 zf = {0.f, 0.f, 0.f, 0.f};
    #pragma unroll
    for (int i = 0; i < 4; ++i)
        #pragma unroll
        for (int j = 0; j < 4; ++j) acc[i][j] = zf;

    auto STAGE = [&](int tile) {
        bf16* buf = smem + (tile % 3) * 8192;
        const int k0 = tile * 32;
        #pragma unroll
        for (int i = 0; i < 2; ++i) {
            const int c   = t + 256 * i;
            const int row = c >> 2;
            const int kb  = ((c & 3) ^ ((row >> 1) & 3)) * 8;
            __builtin_amdgcn_global_load_lds(
                (const AS1 void*)(Ap + (size_t)(m0 + row) * KDEPTH + k0 + kb),
                (AS3 void*)(buf + c * 8), 16, 0, 0);
            __builtin_amdgcn_global_load_lds(
                (const AS1 void*)(Bp + (size_t)(n0 + row) * KDEPTH + k0 + kb),
                (AS3 void*)(buf + 4096 + c * 8), 16, 0, 0);
        }
    };

    auto COMPUTE = [&](int bufi) {
        const bf16* AsP = smem + bufi * 8192;
        const bf16* BsP = AsP + 4096;
        bf16x8 af[4], bfv[4];
        #pragma unroll
        for (int i = 0; i < 4; ++i) {
            const int ar = wr * 64 + i * 16 + (lane & 15);
            const int ja = (lane >> 4) ^ ((ar >> 1) & 3);
            af[i]  = *(const bf16x8*)(AsP + ar * 32 + ja * 8);
            const int br = wc * 64 + i * 16 + (lane & 15);
            const int jb = (lane >> 4) ^ ((br >> 1) & 3);
            bfv[i] = *(const bf16x8*)(BsP + br * 32 + jb * 8);
        }
        __builtin_amdgcn_s_setprio(1);
        #pragma unroll
        for (int i = 0; i < 4; ++i)
            #pragma unroll
            for (int j = 0; j < 4; ++j)
                acc[i][j] = __builtin_amdgcn_mfma_f32_16x16x32_bf16(
                    af[i], bfv[j], acc[i][j], 0, 0, 0);
        __builtin_amdgcn_s_setprio(0);
    };

    // prologue: 2-deep prefetch; wait tile0 (allow tile1's 4 loads in flight)
    STAGE(0); STAGE(1);
    asm volatile("s_waitcnt vmcnt(4)" ::: "memory");
    asm volatile("s_barrier" ::: "memory");

    int cur = 0;
    for (int kt = 0; kt < 14; ++kt) {
        STAGE(kt + 2);                 // buf (kt+2)%3: readers done at kt-1 bar
        COMPUTE(cur);
        __builtin_amdgcn_sched_barrier(0);
        asm volatile("s_waitcnt vmcnt(4)" ::: "memory");   // tile kt+1 landed
        asm volatile("s_barrier" ::: "memory");
        cur = (cur + 1) % 3;
    }
    COMPUTE(cur);                      // kt = 14
    __builtin_amdgcn_sched_barrier(0);
    asm volatile("s_waitcnt vmcnt(0)" ::: "memory");       // tile 15 landed
    asm volatile("s_barrier" ::: "memory");
    cur = (cur + 1) % 3;
    COMPUTE(cur);                      // kt = 15
    __syncthreads();

    // LDS-bounce coalesced bf16 epilogue (32 KB tile fits the ring space)
    {
        bf16* ct = smem;
        #pragma unroll
        for (int i = 0; i < 4; ++i) {
            const int ml = wr * 64 + i * 16 + (lane >> 4) * 4;
            #pragma unroll
            for (int r = 0; r < 4; ++r) {
                const float bv = bias[m0 + ml + r];
                #pragma unroll
                for (int j = 0; j < 4; ++j) {
                    const int n = wc * 64 + j * 16 + (lane & 15);
                    ct[(ml + r) * 128 + n] = (bf16)(acc[i][j][r] + bv);
                }
            }
        }
        __syncthreads();
        bf16* Qp = qkb + (size_t)b * QKROWS * NPIX;
        #pragma unroll
        for (int ii = 0; ii < 8; ++ii) {
            const int c   = t + 256 * ii;
            const int row = c >> 4;
            const int seg = c & 15;
            const int4 v = *(const int4*)(ct + row * 128 + seg * 8);
            *(int4*)(Qp + (size_t)(m0 + row) * NPIX + n0 + seg * 8) = v;
        }
    }
}

// ---------------------------------------------------------------------------
// QK^T split-K partial (MFMA): NSPLIT=8, 512 n per split.
// ---------------------------------------------------------------------------
__global__ __launch_bounds__(256) void qk_partial_kernel(
    const bf16* __restrict__ qk, float* __restrict__ part)
{
    const int s  = blockIdx.x;
    const int bh = blockIdx.y;
    const int b = bh >> 3, h = bh & 7;
    const bf16* qbase = qk + ((size_t)b * QKROWS + h * HDIM) * NPIX;
    const bf16* kbase = qk + ((size_t)b * QKROWS + CH + h * HDIM) * NPIX;

    __shared__ bf16 smem[16384];

    const int t    = threadIdx.x;
    const int lane = t & 63;
    const int wave = t >> 6;

    f32x4 acc[4];
    const f32x4 zf = {0.f, 0.f, 0.f, 0.f};
    #pragma unroll
    for (int j = 0; j < 4; ++j) acc[j] = zf;

    auto STAGE = [&](int p, int n0) {
        #pragma unroll
        for (int i = 0; i < 2; ++i) {
            const int c   = t + 256 * i;
            const int row = c >> 3;
            const int nb  = ((c & 7) ^ (row & 7)) * 8;
            __builtin_amdgcn_global_load_lds(
                (const AS1 void*)(qbase + (size_t)row * NPIX + n0 + nb),
                (AS3 void*)(smem + p * 8192 + c * 8), 16, 0, 0);
            __builtin_amdgcn_global_load_lds(
                (const AS1 void*)(kbase + (size_t)row * NPIX + n0 + nb),
                (AS3 void*)(smem + p * 8192 + 4096 + c * 8), 16, 0, 0);
        }
    };

    STAGE(0, s * 512);
    __syncthreads();
    int cur = 0;

    for (int nc = 0; nc < 8; ++nc) {
        if (nc < 7) STAGE(cur ^ 1, s * 512 + (nc + 1) * 64);

        const bf16* Qs = smem + cur * 8192;
        const bf16* Ks = Qs + 4096;
        #pragma unroll
        for (int ks = 0; ks < 2; ++ks) {
            const int dr = wave * 16 + (lane & 15);
            const int ja = (ks * 4 + (lane >> 4)) ^ (dr & 7);
            const bf16x8 af = *(const bf16x8*)(Qs + dr * 64 + ja * 8);
            #pragma unroll
            for (int j = 0; j < 4; ++j) {
                const int er = j * 16 + (lane & 15);
                const int jb = (ks * 4 + (lane >> 4)) ^ (er & 7);
                const bf16x8 bf_ = *(const bf16x8*)(Ks + er * 64 + jb * 8);
                acc[j] = __builtin_amdgcn_mfma_f32_16x16x32_bf16(af, bf_, acc[j], 0, 0, 0);
            }
        }
        __syncthreads();
        cur ^= 1;
    }

    float* pb = part + (((size_t)bh * NSPLIT + s) * 64) * 64;
    #pragma unroll
    for (int j = 0; j < 4; ++j)
        #pragma unroll
        for (int r = 0; r < 4; ++r)
            pb[(size_t)(wave * 16 + (lane >> 4) * 4 + r) * 64 + j * 16 + (lane & 15)] = acc[j][r];
}

// ---------------------------------------------------------------------------
// Reduce partials + row softmax -> attn[bh][d][e] fp32
// ---------------------------------------------------------------------------
__global__ __launch_bounds__(256) void qk_reduce_softmax_kernel(
    const float* __restrict__ part, float* __restrict__ attn)
{
    const int bh = blockIdx.x;
    const int t  = threadIdx.x;
    const int r  = t >> 2;
    const int e0 = (t & 3) * 16;

    float v[16];
    #pragma unroll
    for (int i = 0; i < 16; ++i) v[i] = 0.f;

    const float* pb = part + ((size_t)bh * NSPLIT * 64) * 64 + r * 64 + e0;
    for (int s = 0; s < NSPLIT; ++s) {
        const float* ps = pb + (size_t)s * 4096;
        #pragma unroll
        for (int c4 = 0; c4 < 4; ++c4) {
            const float4 p = *(const float4*)(ps + c4 * 4);
            v[c4 * 4 + 0] += p.x; v[c4 * 4 + 1] += p.y;
            v[c4 * 4 + 2] += p.z; v[c4 * 4 + 3] += p.w;
        }
    }

    float m = -1e30f;
    #pragma unroll
    for (int i = 0; i < 16; ++i) m = fmaxf(m, v[i]);
    m = fmaxf(m, __shfl_xor(m, 1));
    m = fmaxf(m, __shfl_xor(m, 2));

    float sum = 0.f;
    #pragma unroll
    for (int i = 0; i < 16; ++i) {
        v[i] = __expf((v[i] - m) * SCALE);
        sum += v[i];
    }
    sum += __shfl_xor(sum, 1);
    sum += __shfl_xor(sum, 2);
    const float inv = 1.f / sum;

    float* arow = attn + ((size_t)bh * 64 + r) * 64 + e0;
    #pragma unroll
    for (int c4 = 0; c4 < 4; ++c4) {
        float4 o;
        o.x = v[c4 * 4 + 0] * inv; o.y = v[c4 * 4 + 1] * inv;
        o.z = v[c4 * 4 + 2] * inv; o.w = v[c4 * 4 + 3] * inv;
        *(float4*)(arow + c4 * 4) = o;
    }
}

// ---------------------------------------------------------------------------
// attn_mean[b][d][e] = mean_h attn[b][h][d][e]
// ---------------------------------------------------------------------------
__global__ __launch_bounds__(256) void attn_mean_kernel(
    const float* __restrict__ attn, float* __restrict__ om)
{
    const int idx = blockIdx.x * 256 + threadIdx.x;
    const int b = idx >> 12, de = idx & 4095;
    float s = 0.f;
    #pragma unroll
    for (int h = 0; h < 8; ++h)
        s += attn[(((size_t)b * 8 + h) << 12) + de];
    om[idx] = s * 0.125f;
}

// ---------------------------------------------------------------------------
// W'[b][o][h*64+e] = sum_d proj_w[o][h*64+d] * attn[b,h,d,e]   (fp32 -> bf16)
// ---------------------------------------------------------------------------
__global__ __launch_bounds__(256) void wprime_kernel(
    const float* __restrict__ proj_w, const float* __restrict__ attn,
    bf16* __restrict__ wp)
{
    const int o0 = blockIdx.x * 64;
    const int h  = blockIdx.y;
    const int b  = blockIdx.z;

    __shared__ float ws[64][65];
    __shared__ float as_[64][65];

    const int t = threadIdx.x;
    #pragma unroll
    for (int i = 0; i < 4; ++i) {
        const int lin = t + 256 * i;
        const int r   = lin >> 4;
        const int c4  = (lin & 15) * 4;
        const float4 wv = *(const float4*)(proj_w + (size_t)(o0 + r) * CH + h * HDIM + c4);
        ws[r][c4 + 0] = wv.x; ws[r][c4 + 1] = wv.y;
        ws[r][c4 + 2] = wv.z; ws[r][c4 + 3] = wv.w;
        const float4 av = *(const float4*)(attn + (((size_t)(b * 8 + h) * 64) + r) * 64 + c4);
        as_[r][c4 + 0] = av.x; as_[r][c4 + 1] = av.y;
        as_[r][c4 + 2] = av.z; as_[r][c4 + 3] = av.w;
    }
    __syncthreads();

    const int tx = t & 15, ty = t >> 4;
    const int to = ty * 4, te = tx * 4;
    float acc[4][4] = {};
    for (int d = 0; d < 64; ++d) {
        float a[4], bb[4];
        #pragma unroll
        for (int i = 0; i < 4; ++i) a[i]  = ws[to + i][d];
        #pragma unroll
        for (int j = 0; j < 4; ++j) bb[j] = as_[d][te + j];
        #pragma unroll
        for (int i = 0; i < 4; ++i)
            #pragma unroll
            for (int j = 0; j < 4; ++j)
                acc[i][j] = fmaf(a[i], bb[j], acc[i][j]);
    }

    bf16* wb = wp + (size_t)b * CH * CH;
    #pragma unroll
    for (int i = 0; i < 4; ++i)
        #pragma unroll
        for (int j = 0; j < 4; ++j)
            wb[(size_t)(o0 + to + i) * CH + h * HDIM + te + j] = (bf16)acc[i][j];
}

// ---------------------------------------------------------------------------
// bias2[b][o] = sum_d W'[b][o][d] * bv[d] + pb[o]
// ---------------------------------------------------------------------------
__global__ __launch_bounds__(256) void bias2_kernel(
    const bf16* __restrict__ wp, const float* __restrict__ bv,
    const float* __restrict__ pb, float* __restrict__ bias2)
{
    const int idx = blockIdx.x * 256 + threadIdx.x;   // < 4096
    const int b = idx >> 9, o = idx & 511;
    const bf16* wr = wp + ((size_t)b * CH + o) * CH;
    float s = 0.f;
    for (int d = 0; d < 512; ++d) s += (float)wr[d] * bv[d];
    bias2[idx] = s + pb[o];
}

// ---------------------------------------------------------------------------
// Generic 128x128 GEMM, K=512, R17 ring pipeline. Cb -> bf16 scalar epilogue
// (tiny W'' use); else fp32 via LDS-bounce. XCD swizzle. bias[b*bstride+m].
// ---------------------------------------------------------------------------
__global__ __launch_bounds__(256) void gemm128_kernel(
    const bf16* __restrict__ A, const bf16* __restrict__ Bt,
    const float* __restrict__ bias, size_t bias_bstride,
    float* __restrict__ Cf, bf16* __restrict__ Cb,
    int ncols, int c_rows, size_t a_bstride, size_t bt_bstride)
{
    const int nwg  = gridDim.x * gridDim.y;
    const int orig = blockIdx.x + gridDim.x * blockIdx.y;
    const int wg   = (orig & 7) * (nwg >> 3) + (orig >> 3);
    const int by   = wg % gridDim.y;
    const int bx   = wg / gridDim.y;

    const int b  = blockIdx.z;
    const int m0 = by * 128;
    const int n0 = bx * 128;
    const bf16* Ap = A  + (size_t)b * a_bstride;
    const bf16* Bp = Bt + (size_t)b * bt_bstride;

    __shared__ bf16 smem[3 * 8192];

    const int t    = threadIdx.x;
    const int lane = t & 63;
    const int wave = t >> 6;
    const int wr   = wave >> 1, wc = wave & 1;

    f32x4 acc[4][4];
    const f32x4 zf = {0.f, 0.f, 0.f, 0.f};
    #pragma unroll
    for (int i = 0; i < 4; ++i)
        #pragma unroll
        for (int j = 0; j < 4; ++j) acc[i][j] = zf;

    auto STAGE = [&](int tile) {
        bf16* buf = smem + (tile % 3) * 8192;
        const int k0 = tile * 32;
        #pragma unroll
        for (int i = 0; i < 2; ++i) {
            const int c   = t + 256 * i;
            const int row = c >> 2;
            const int kb  = ((c & 3) ^ ((row >> 1) & 3)) * 8;
            __builtin_amdgcn_global_load_lds(
                (const AS1 void*)(Ap + (size_t)(m0 + row) * KDEPTH + k0 + kb),
                (AS3 void*)(buf + c * 8), 16, 0, 0);
            __builtin_amdgcn_global_load_lds(
                (const AS1 void*)(Bp + (size_t)(n0 + row) * KDEPTH + k0 + kb),
                (AS3 void*)(buf + 4096 + c * 8), 16, 0, 0);
        }
    };

    auto COMPUTE = [&](int bufi) {
        const bf16* AsP = smem + bufi * 8192;
        const bf16* BsP = AsP + 4096;
        bf16x8 af[4], bfv[4];
        #pragma unroll
        for (int i = 0; i < 4; ++i) {
            const int ar = wr * 64 + i * 16 + (lane & 15);
            const int ja = (lane >> 4) ^ ((ar >> 1) & 3);
            af[i]  = *(const bf16x8*)(AsP + ar * 32 + ja * 8);
            const int br = wc * 64 + i * 16 + (lane & 15);
            const int jb = (lane >> 4) ^ ((br >> 1) & 3);
            bfv[i] = *(const bf16x8*)(BsP + br * 32 + jb * 8);
        }
        __builtin_amdgcn_s_setprio(1);
        #pragma unroll
        for (int i = 0; i < 4; ++i)
            #pragma unroll
            for (int j = 0; j < 4; ++j)
                acc[i][j] = __builtin_amdgcn_mfma_f32_16x16x32_bf16(
                    af[i], bfv[j], acc[i][j], 0, 0, 0);
        __builtin_amdgcn_s_setprio(0);
    };

    STAGE(0); STAGE(1);
    asm volatile("s_waitcnt vmcnt(4)" ::: "memory");
    asm volatile("s_barrier" ::: "memory");

    int cur = 0;
    for (int kt = 0; kt < 14; ++kt) {
        STAGE(kt + 2);
        COMPUTE(cur);
        __builtin_amdgcn_sched_barrier(0);
        asm volatile("s_waitcnt vmcnt(4)" ::: "memory");
        asm volatile("s_barrier" ::: "memory");
        cur = (cur + 1) % 3;
    }
    COMPUTE(cur);
    __builtin_amdgcn_sched_barrier(0);
    asm volatile("s_waitcnt vmcnt(0)" ::: "memory");
    asm volatile("s_barrier" ::: "memory");
    cur = (cur + 1) % 3;
    COMPUTE(cur);
    __syncthreads();

    if (Cb) {
        #pragma unroll
        for (int i = 0; i < 4; ++i) {
            const int mb = m0 + wr * 64 + i * 16 + (lane >> 4) * 4;
            #pragma unroll
            for (int r = 0; r < 4; ++r) {
                const int m  = mb + r;
                const float bv = bias ? bias[b * bias_bstride + m] : 0.f;
                #pragma unroll
                for (int j = 0; j < 4; ++j) {
                    const int n = n0 + wc * 64 + j * 16 + (lane & 15);
                    Cb[(size_t)b * c_rows * ncols + (size_t)m * ncols + n] =
                        (bf16)(acc[i][j][r] + bv);
                }
            }
        }
    } else {
        float* ct = (float*)smem;
        float* Cp = Cf + (size_t)b * c_rows * ncols;
        #pragma unroll
        for (int p = 0; p < 2; ++p) {
            if (wc == p) {
                #pragma unroll
                for (int i = 0; i < 4; ++i) {
                    const int ml = wr * 64 + i * 16 + (lane >> 4) * 4;
                    #pragma unroll
                    for (int r = 0; r < 4; ++r) {
                        const float bv = bias ? bias[b * bias_bstride + m0 + ml + r] : 0.f;
                        #pragma unroll
                        for (int j = 0; j < 4; ++j) {
                            const int n = j * 16 + (lane & 15);
                            ct[(ml + r) * 64 + n] = acc[i][j][r] + bv;
                        }
                    }
                }
            }
            __syncthreads();
            #pragma unroll
            for (int ii = 0; ii < 8; ++ii) {
                const int c   = t + 256 * ii;
                const int row = c >> 4;
                const int seg = c & 15;
                const float4 v = *(const float4*)(ct + row * 64 + seg * 4);
                *(float4*)(Cp + (size_t)(m0 + row) * ncols + n0 + p * 64 + seg * 4) = v;
            }
            __syncthreads();
        }
    }
}

// ---------------------------------------------------------------------------
extern "C" void kernel_launch(void* const* d_in, const int* in_sizes, int n_in,
                              void* d_out, int out_size, void* d_ws, size_t ws_size,
                              hipStream_t stream)
{
    (void)in_sizes; (void)n_in; (void)out_size;
    const float* x      = (const float*)d_in[0];
    const float* qkv_w  = (const float*)d_in[1];
    const float* qkv_b  = (const float*)d_in[2];
    const float* proj_w = (const float*)d_in[3];
    const float* proj_b = (const float*)d_in[4];

    float* out       = (float*)d_out;
    float* attn_mean = out + (size_t)BATCH * CH * NPIX;

    const size_t qk_bytes   = (size_t)BATCH * QKROWS * NPIX * 2;        //  64 MiB
    const size_t xt_bytes   = (size_t)BATCH * NPIX * CH * 2;            //  32 MiB
    const size_t wq_bytes   = (size_t)OC3 * KDEPTH * 2;                 // 1.5 MiB
    const size_t attn_bytes = (size_t)BATCH * HEADS * HDIM * HDIM * 4;  //   1 MiB
    const size_t part_bytes = (size_t)BATCH * HEADS * NSPLIT * HDIM * HDIM * 4; // 8 MiB
    const size_t wp_bytes   = (size_t)BATCH * CH * CH * 2;              //   4 MiB
    const size_t wpp_bytes  = (size_t)BATCH * CH * CH * 2;              //   4 MiB
    const size_t wvt_bytes  = (size_t)CH * CH * 2;                      // 0.5 MiB
    const size_t b2_bytes   = (size_t)BATCH * CH * 4;                   //  16 KiB
    const size_t need = qk_bytes + xt_bytes + wq_bytes + attn_bytes + part_bytes +
                        wp_bytes + wpp_bytes + wvt_bytes + b2_bytes;
    if (ws_size < need) {
        fprintf(stderr, "[kernel_launch] ws_size=%zu < need=%zu — abort\n", ws_size, need);
        fflush(stderr);
        return;
    }

    char* p = (char*)d_ws;
    bf16*  qk     = (bf16*)p;             p += qk_bytes;
    bf16*  xt     = (bf16*)p;             p += xt_bytes;
    bf16*  wq_b   = (bf16*)p;             p += wq_bytes;
    float* attn   = (float*)p;            p += attn_bytes;
    float* part   = (float*)p;            p += part_bytes;
    bf16*  wprime = (bf16*)p;             p += wp_bytes;
    bf16*  wpp    = (bf16*)p;             p += wpp_bytes;
    bf16*  wvt    = (bf16*)p;             p += wvt_bytes;
    float* bias2  = (float*)p;

    // 0) weight convert + Wv^T (merged)
    convert_wvt_kernel<<<dim3((OC3 * KDEPTH) / 256 + 64), 256, 0, stream>>>(
        qkv_w, wq_b, wvt);

    // 1) x -> xt (transpose + bf16)
    transpose_convert_kernel<<<dim3(NPIX / 64, CH / 64, BATCH), 256, 0, stream>>>(x, xt);

    // 2) Q,K GEMM -> bf16 qk[b][1024][4096] (c-major)
    gemm_qk_kernel<<<dim3(NPIX / 128, QKROWS / 128, BATCH), 256, 0, stream>>>(
        wq_b, xt, qkv_b, qk);

    // 3) QK^T split-K (MFMA) + softmax
    qk_partial_kernel<<<dim3(NSPLIT, BATCH * HEADS), 256, 0, stream>>>(qk, part);
    qk_reduce_softmax_kernel<<<dim3(BATCH * HEADS), 256, 0, stream>>>(part, attn);

    // 4) attn mean over heads (output 1)
    attn_mean_kernel<<<dim3(BATCH * HDIM * HDIM / 256), 256, 0, stream>>>(attn, attn_mean);

    // 5) W' = proj_w · blockdiag(attn)
    wprime_kernel<<<dim3(CH / 64, HEADS, BATCH), 256, 0, stream>>>(proj_w, attn, wprime);

    // 6) W'' = W' · Wv (bf16) ; bias'' = W'·bv + pb
    gemm128_kernel<<<dim3(CH / 128, CH / 128, BATCH), 256, 0, stream>>>(
        wprime, wvt, nullptr, 0, nullptr, wpp, CH, CH, (size_t)CH * CH, 0);
    bias2_kernel<<<dim3(BATCH * CH / 256), 256, 0, stream>>>(
        wprime, qkv_b + 2 * CH, proj_b, bias2);

    // 7) out = W''_b · x + bias''  (fp32 coalesced epilogue)
    gemm128_kernel<<<dim3(NPIX / 128, CH / 128, BATCH), 256, 0, stream>>>(
        wpp, xt, bias2, CH, out, nullptr, NPIX, CH, (size_t)CH * CH,
        (size_t)NPIX * KDEPTH);
}

// Round 18
// 140.819 us; speedup vs baseline: 1.3434x; 1.0744x over previous
//
#include <hip/hip_runtime.h>
#include <cstdio>
#include <cstdint>

// Problem constants
#define BATCH 8
#define CH    512
#define OC3   1536      // 3*CH
#define NPIX  4096      // 64*64
#define HEADS 8
#define HDIM  64
#define KDEPTH 512
#define SCALE 0.125f    // 64^-0.5
#define NSPLIT 32       // S-partials per (b,h): one per 128-n window

typedef __bf16 bf16;
typedef __bf16 bf16x4 __attribute__((ext_vector_type(4)));
typedef __bf16 bf16x8 __attribute__((ext_vector_type(8)));
typedef float  f32x4  __attribute__((ext_vector_type(4)));

#define AS1 __attribute__((address_space(1)))
#define AS3 __attribute__((address_space(3)))

// ---------------------------------------------------------------------------
// Merged: fp32 -> bf16 flat convert of qkv_w (blocks 0..3071)  +
//         Wv^T build: wvt[c][d] (blocks 3072..3135)
// ---------------------------------------------------------------------------
__global__ __launch_bounds__(256) void convert_wvt_kernel(
    const float* __restrict__ qkv_w, bf16* __restrict__ wq_b,
    bf16* __restrict__ wvt)
{
    const int bid = blockIdx.x;
    const int t = threadIdx.x;
    if (bid < (OC3 * KDEPTH) / 256) {
        const int i = bid * 256 + t;
        wq_b[i] = (bf16)qkv_w[i];
        return;
    }
    const int tb = bid - (OC3 * KDEPTH) / 256;   // 0..63
    const int c0 = (tb & 7) * 64;
    const int d0 = (tb >> 3) * 64;
    __shared__ float tl[64][68];
    const float* wv = qkv_w + (size_t)2 * CH * KDEPTH;
    #pragma unroll
    for (int i = 0; i < 4; ++i) {
        const int lin = t + 256 * i;
        const int row = lin >> 4;
        const int c4  = (lin & 15) * 4;
        const float4 v = *(const float4*)(wv + (size_t)(d0 + row) * CH + c0 + c4);
        tl[row][c4 + 0] = v.x; tl[row][c4 + 1] = v.y;
        tl[row][c4 + 2] = v.z; tl[row][c4 + 3] = v.w;
    }
    __syncthreads();
    #pragma unroll
    for (int i = 0; i < 2; ++i) {
        const int lin  = t + 256 * i;
        const int crow = lin >> 3;
        const int d8   = (lin & 7) * 8;
        bf16x8 v;
        #pragma unroll
        for (int j = 0; j < 8; ++j) v[j] = (bf16)tl[d8 + j][crow];
        *(bf16x8*)(wvt + (size_t)(c0 + crow) * CH + d0 + d8) = v;
    }
}

// ---------------------------------------------------------------------------
// x [b][512][4096] fp32 -> xt [b][4096][512] bf16 (transpose)
// ---------------------------------------------------------------------------
__global__ __launch_bounds__(256) void transpose_convert_kernel(
    const float* __restrict__ src, bf16* __restrict__ dst)
{
    const int b  = blockIdx.z;
    const int n0 = blockIdx.x * 64;
    const int c0 = blockIdx.y * 64;
    __shared__ float tile[64][65];
    const int t = threadIdx.x;
    const float* xp = src + (size_t)b * CH * NPIX;

    #pragma unroll
    for (int i = 0; i < 4; ++i) {
        const int lin = t + 256 * i;
        const int r   = lin >> 4;
        const int c4  = (lin & 15) * 4;
        const float4 v = *(const float4*)(xp + (size_t)(c0 + r) * 4096 + n0 + c4);
        tile[r][c4 + 0] = v.x; tile[r][c4 + 1] = v.y;
        tile[r][c4 + 2] = v.z; tile[r][c4 + 3] = v.w;
    }
    __syncthreads();

    bf16* op = dst + (size_t)b * NPIX * CH;
    #pragma unroll
    for (int i = 0; i < 2; ++i) {
        const int lin = t + 256 * i;
        const int n   = lin >> 3;
        const int c8  = (lin & 7) * 8;
        bf16x8 v;
        #pragma unroll
        for (int jj = 0; jj < 8; ++jj) v[jj] = (bf16)tile[c8 + jj][n];
        *(bf16x8*)(op + (size_t)(n0 + n) * CH + c0 + c8) = v;
    }
}

// ---------------------------------------------------------------------------
// Fused Q/K GEMM + QK^T partial. Block (nwin=bx, head=by, b):
//   tile = [Q_head(64) ; K_head(64)] x 128 n-values (A rows remapped per head),
//   then S_partial[d][e] = sum_{n in win} Q[d,n]K[e,n] -> part (fp32).
// Main loop: R17 ring (3 bufs, counted vmcnt(4), setprio). No qk in global.
// ---------------------------------------------------------------------------
__global__ __launch_bounds__(256) void gemm_qks_kernel(
    const bf16* __restrict__ A, const bf16* __restrict__ Bt,
    const float* __restrict__ qkv_b, float* __restrict__ part)
{
    const int nwg  = gridDim.x * gridDim.y;          // 256
    const int orig = blockIdx.x + gridDim.x * blockIdx.y;
    const int wg   = (orig & 7) * (nwg >> 3) + (orig >> 3);
    const int head = wg % gridDim.y;
    const int bx   = wg / gridDim.y;

    const int b  = blockIdx.z;
    const int n0 = bx * 128;
    const bf16* Bp = Bt + (size_t)b * NPIX * KDEPTH;

    __shared__ bf16 smem[3 * 8192];   // ring (48 KB); epilogue reuses 32 KB

    const int t    = threadIdx.x;
    const int lane = t & 63;
    const int wave = t >> 6;
    const int wr   = wave >> 1, wc = wave & 1;

    f32x4 acc[4][4];
    const f32x4 zf = {0.f, 0.f, 0.f, 0.f};
    #pragma unroll
    for (int i = 0; i < 4; ++i)
        #pragma unroll
        for (int j = 0; j < 4; ++j) acc[i][j] = zf;

    auto STAGE = [&](int tile) {
        bf16* buf = smem + (tile % 3) * 8192;
        const int k0 = tile * 32;
        #pragma unroll
        for (int i = 0; i < 2; ++i) {
            const int c   = t + 256 * i;
            const int lr  = c >> 2;          // LDS row 0..127
            const int kb  = ((c & 3) ^ ((lr >> 1) & 3)) * 8;
            // A-row remap: rows 0..63 = Wq[head*64+lr], 64..127 = Wk[head*64+lr-64]
            const int src = (lr < 64) ? (head * HDIM + lr)
                                      : (CH + head * HDIM + (lr - 64));
            __builtin_amdgcn_global_load_lds(
                (const AS1 void*)(A + (size_t)src * KDEPTH + k0 + kb),
                (AS3 void*)(buf + c * 8), 16, 0, 0);
            __builtin_amdgcn_global_load_lds(
                (const AS1 void*)(Bp + (size_t)(n0 + lr) * KDEPTH + k0 + kb),
                (AS3 void*)(buf + 4096 + c * 8), 16, 0, 0);
        }
    };

    auto COMPUTE = [&](int bufi) {
        const bf16* AsP = smem + bufi * 8192;
        const bf16* BsP = AsP + 4096;
        bf16x8 af[4], bfv[4];
        #pragma unroll
        for (int i = 0; i < 4; ++i) {
            const int ar = wr * 64 + i * 16 + (lane & 15);
            const int ja = (lane >> 4) ^ ((ar >> 1) & 3);
            af[i]  = *(const bf16x8*)(AsP + ar * 32 + ja * 8);
            const int br = wc * 64 + i * 16 + (lane & 15);
            const int jb = (lane >> 4) ^ ((br >> 1) & 3);
            bfv[i] = *(const bf16x8*)(BsP + br * 32 + jb * 8);
        }
        __builtin_amdgcn_s_setprio(1);
        #pragma unroll
        for (int i = 0; i < 4; ++i)
            #pragma unroll
            for (int j = 0; j < 4; ++j)
                acc[i][j] = __builtin_amdgcn_mfma_f32_16x16x32_bf16(
                    af[i], bfv[j], acc[i][j], 0, 0, 0);
        __builtin_amdgcn_s_setprio(0);
    };

    STAGE(0); STAGE(1);
    asm volatile("s_waitcnt vmcnt(4)" ::: "memory");
    asm volatile("s_barrier" ::: "memory");

    int cur = 0;
    for (int kt = 0; kt < 14; ++kt) {
        STAGE(kt + 2);
        COMPUTE(cur);
        __builtin_amdgcn_sched_barrier(0);
        asm volatile("s_waitcnt vmcnt(4)" ::: "memory");
        asm volatile("s_barrier" ::: "memory");
        cur = (cur + 1) % 3;
    }
    COMPUTE(cur);
    __builtin_amdgcn_sched_barrier(0);
    asm volatile("s_waitcnt vmcnt(0)" ::: "memory");
    asm volatile("s_barrier" ::: "memory");
    cur = (cur + 1) % 3;
    COMPUTE(cur);
    __syncthreads();

    // Bounce: acc (+bias) -> ct[128 rows][128 n] bf16, chunk-slot ^ (row&15)
    bf16* ct = smem;
    #pragma unroll
    for (int i = 0; i < 4; ++i) {
        const int mlb = wr * 64 + i * 16 + (lane >> 4) * 4;
        #pragma unroll
        for (int r = 0; r < 4; ++r) {
            const int row = mlb + r;
            const int bsrc = (row < 64) ? (head * HDIM + row)
                                        : (CH + head * HDIM + (row - 64));
            const float bv = qkv_b[bsrc];
            #pragma unroll
            for (int j = 0; j < 4; ++j) {
                const int n = wc * 64 + j * 16 + (lane & 15);
                ct[row * 128 + (((n >> 3) ^ (row & 15)) * 8) + (n & 7)] =
                    (bf16)(acc[i][j][r] + bv);
            }
        }
    }
    __syncthreads();

    // S-partial: wave w -> e-range w*16..+16. 4 ksteps of 32 n.
    f32x4 sacc[4];
    #pragma unroll
    for (int df = 0; df < 4; ++df) sacc[df] = zf;
    #pragma unroll
    for (int ks = 0; ks < 4; ++ks) {
        const int slot8 = ((ks * 4 + (lane >> 4)) ^ (lane & 15)) * 8;
        const bf16x8 kf = *(const bf16x8*)(ct + (64 + wave * 16 + (lane & 15)) * 128 + slot8);
        #pragma unroll
        for (int df = 0; df < 4; ++df) {
            const bf16x8 qf = *(const bf16x8*)(ct + (df * 16 + (lane & 15)) * 128 + slot8);
            sacc[df] = __builtin_amdgcn_mfma_f32_16x16x32_bf16(qf, kf, sacc[df], 0, 0, 0);
        }
    }

    float* pp = part + (((size_t)(b * 8 + head) * NSPLIT + bx) * 64) * 64;
    #pragma unroll
    for (int df = 0; df < 4; ++df)
        #pragma unroll
        for (int r = 0; r < 4; ++r)
            pp[(size_t)(df * 16 + (lane >> 4) * 4 + r) * 64 + wave * 16 + (lane & 15)]
                = sacc[df][r];
}

// ---------------------------------------------------------------------------
// Reduce 32 partials + row softmax -> attn[bh][d][e] fp32. grid (8, 64).
// Block (rg, bh): rows rg*8..+8; 32 threads per row, 2 e-values each.
// ---------------------------------------------------------------------------
__global__ __launch_bounds__(256) void qk_reduce_softmax_kernel(
    const float* __restrict__ part, float* __restrict__ attn)
{
    const int rg = blockIdx.x, bh = blockIdx.y;
    const int t  = threadIdx.x;
    const int row = rg * 8 + (t >> 5);
    const int le  = t & 31;

    const float* pb = part + (size_t)bh * NSPLIT * 4096 + row * 64;
    float v0 = 0.f, v1 = 0.f;
    #pragma unroll 8
    for (int s = 0; s < NSPLIT; ++s) {
        v0 += pb[(size_t)s * 4096 + le];
        v1 += pb[(size_t)s * 4096 + 32 + le];
    }

    float m = fmaxf(v0, v1);
    m = fmaxf(m, __shfl_xor(m, 1));
    m = fmaxf(m, __shfl_xor(m, 2));
    m = fmaxf(m, __shfl_xor(m, 4));
    m = fmaxf(m, __shfl_xor(m, 8));
    m = fmaxf(m, __shfl_xor(m, 16));

    v0 = __expf((v0 - m) * SCALE);
    v1 = __expf((v1 - m) * SCALE);
    float sum = v0 + v1;
    sum += __shfl_xor(sum, 1);
    sum += __shfl_xor(sum, 2);
    sum += __shfl_xor(sum, 4);
    sum += __shfl_xor(sum, 8);
    sum += __shfl_xor(sum, 16);
    const float inv = 1.f / sum;

    float* arow = attn + ((size_t)bh * 64 + row) * 64;
    arow[le]      = v0 * inv;
    arow[32 + le] = v1 * inv;
}

// ---------------------------------------------------------------------------
// attn_mean[b][d][e] = mean_h attn[b][h][d][e]
// ---------------------------------------------------------------------------
__global__ __launch_bounds__(256) void attn_mean_kernel(
    const float* __restrict__ attn, float* __restrict__ om)
{
    const int idx = blockIdx.x * 256 + threadIdx.x;
    const int b = idx >> 12, de = idx & 4095;
    float s = 0.f;
    #pragma unroll
    for (int h = 0; h < 8; ++h)
        s += attn[(((size_t)b * 8 + h) << 12) + de];
    om[idx] = s * 0.125f;
}

// ---------------------------------------------------------------------------
// W'[b][o][h*64+e] = sum_d proj_w[o][h*64+d] * attn[b,h,d,e]   (fp32 -> bf16)
// ---------------------------------------------------------------------------
__global__ __launch_bounds__(256) void wprime_kernel(
    const float* __restrict__ proj_w, const float* __restrict__ attn,
    bf16* __restrict__ wp)
{
    const int o0 = blockIdx.x * 64;
    const int h  = blockIdx.y;
    const int b  = blockIdx.z;

    __shared__ float ws[64][65];
    __shared__ float as_[64][65];

    const int t = threadIdx.x;
    #pragma unroll
    for (int i = 0; i < 4; ++i) {
        const int lin = t + 256 * i;
        const int r   = lin >> 4;
        const int c4  = (lin & 15) * 4;
        const float4 wv = *(const float4*)(proj_w + (size_t)(o0 + r) * CH + h * HDIM + c4);
        ws[r][c4 + 0] = wv.x; ws[r][c4 + 1] = wv.y;
        ws[r][c4 + 2] = wv.z; ws[r][c4 + 3] = wv.w;
        const float4 av = *(const float4*)(attn + (((size_t)(b * 8 + h) * 64) + r) * 64 + c4);
        as_[r][c4 + 0] = av.x; as_[r][c4 + 1] = av.y;
        as_[r][c4 + 2] = av.z; as_[r][c4 + 3] = av.w;
    }
    __syncthreads();

    const int tx = t & 15, ty = t >> 4;
    const int to = ty * 4, te = tx * 4;
    float acc[4][4] = {};
    for (int d = 0; d < 64; ++d) {
        float a[4], bb[4];
        #pragma unroll
        for (int i = 0; i < 4; ++i) a[i]  = ws[to + i][d];
        #pragma unroll
        for (int j = 0; j < 4; ++j) bb[j] = as_[d][te + j];
        #pragma unroll
        for (int i = 0; i < 4; ++i)
            #pragma unroll
            for (int j = 0; j < 4; ++j)
                acc[i][j] = fmaf(a[i], bb[j], acc[i][j]);
    }

    bf16* wb = wp + (size_t)b * CH * CH;
    #pragma unroll
    for (int i = 0; i < 4; ++i)
        #pragma unroll
        for (int j = 0; j < 4; ++j)
            wb[(size_t)(o0 + to + i) * CH + h * HDIM + te + j] = (bf16)acc[i][j];
}

// ---------------------------------------------------------------------------
// bias2[b][o] = sum_d W'[b][o][d] * bv[d] + pb[o]
// ---------------------------------------------------------------------------
__global__ __launch_bounds__(256) void bias2_kernel(
    const bf16* __restrict__ wp, const float* __restrict__ bv,
    const float* __restrict__ pb, float* __restrict__ bias2)
{
    const int idx = blockIdx.x * 256 + threadIdx.x;   // < 4096
    const int b = idx >> 9, o = idx & 511;
    const bf16* wr = wp + ((size_t)b * CH + o) * CH;
    float s = 0.f;
    for (int d = 0; d < 512; ++d) s += (float)wr[d] * bv[d];
    bias2[idx] = s + pb[o];
}

// ---------------------------------------------------------------------------
// Generic 128x128 GEMM, K=512, ring pipeline (R17). Cb -> bf16 scalar
// epilogue (tiny W'' use); else fp32 via LDS-bounce. XCD swizzle.
// ---------------------------------------------------------------------------
__global__ __launch_bounds__(256) void gemm128_kernel(
    const bf16* __restrict__ A, const bf16* __restrict__ Bt,
    const float* __restrict__ bias, size_t bias_bstride,
    float* __restrict__ Cf, bf16* __restrict__ Cb,
    int ncols, int c_rows, size_t a_bstride, size_t bt_bstride)
{
    const int nwg  = gridDim.x * gridDim.y;
    const int orig = blockIdx.x + gridDim.x * blockIdx.y;
    const int wg   = (orig & 7) * (nwg >> 3) + (orig >> 3);
    const int by   = wg % gridDim.y;
    const int bx   = wg / gridDim.y;

    const int b  = blockIdx.z;
    const int m0 = by * 128;
    const int n0 = bx * 128;
    const bf16* Ap = A  + (size_t)b * a_bstride;
    const bf16* Bp = Bt + (size_t)b * bt_bstride;

    __shared__ bf16 smem[3 * 8192];

    const int t    = threadIdx.x;
    const int lane = t & 63;
    const int wave = t >> 6;
    const int wr   = wave >> 1, wc = wave & 1;

    f32x4 acc[4][4];
    const f32x4 zf = {0.f, 0.f, 0.f, 0.f};
    #pragma unroll
    for (int i = 0; i < 4; ++i)
        #pragma unroll
        for (int j = 0; j < 4; ++j) acc[i][j] = zf;

    auto STAGE = [&](int tile) {
        bf16* buf = smem + (tile % 3) * 8192;
        const int k0 = tile * 32;
        #pragma unroll
        for (int i = 0; i < 2; ++i) {
            const int c   = t + 256 * i;
            const int row = c >> 2;
            const int kb  = ((c & 3) ^ ((row >> 1) & 3)) * 8;
            __builtin_amdgcn_global_load_lds(
                (const AS1 void*)(Ap + (size_t)(m0 + row) * KDEPTH + k0 + kb),
                (AS3 void*)(buf + c * 8), 16, 0, 0);
            __builtin_amdgcn_global_load_lds(
                (const AS1 void*)(Bp + (size_t)(n0 + row) * KDEPTH + k0 + kb),
                (AS3 void*)(buf + 4096 + c * 8), 16, 0, 0);
        }
    };

    auto COMPUTE = [&](int bufi) {
        const bf16* AsP = smem + bufi * 8192;
        const bf16* BsP = AsP + 4096;
        bf16x8 af[4], bfv[4];
        #pragma unroll
        for (int i = 0; i < 4; ++i) {
            const int ar = wr * 64 + i * 16 + (lane & 15);
            const int ja = (lane >> 4) ^ ((ar >> 1) & 3);
            af[i]  = *(const bf16x8*)(AsP + ar * 32 + ja * 8);
            const int br = wc * 64 + i * 16 + (lane & 15);
            const int jb = (lane >> 4) ^ ((br >> 1) & 3);
            bfv[i] = *(const bf16x8*)(BsP + br * 32 + jb * 8);
        }
        __builtin_amdgcn_s_setprio(1);
        #pragma unroll
        for (int i = 0; i < 4; ++i)
            #pragma unroll
            for (int j = 0; j < 4; ++j)
                acc[i][j] = __builtin_amdgcn_mfma_f32_16x16x32_bf16(
                    af[i], bfv[j], acc[i][j], 0, 0, 0);
        __builtin_amdgcn_s_setprio(0);
    };

    STAGE(0); STAGE(1);
    asm volatile("s_waitcnt vmcnt(4)" ::: "memory");
    asm volatile("s_barrier" ::: "memory");

    int cur = 0;
    for (int kt = 0; kt < 14; ++kt) {
        STAGE(kt + 2);
        COMPUTE(cur);
        __builtin_amdgcn_sched_barrier(0);
        asm volatile("s_waitcnt vmcnt(4)" ::: "memory");
        asm volatile("s_barrier" ::: "memory");
        cur = (cur + 1) % 3;
    }
    COMPUTE(cur);
    __builtin_amdgcn_sched_barrier(0);
    asm volatile("s_waitcnt vmcnt(0)" ::: "memory");
    asm volatile("s_barrier" ::: "memory");
    cur = (cur + 1) % 3;
    COMPUTE(cur);
    __syncthreads();

    if (Cb) {
        #pragma unroll
        for (int i = 0; i < 4; ++i) {
            const int mb = m0 + wr * 64 + i * 16 + (lane >> 4) * 4;
            #pragma unroll
            for (int r = 0; r < 4; ++r) {
                const int m  = mb + r;
                const float bv = bias ? bias[b * bias_bstride + m] : 0.f;
                #pragma unroll
                for (int j = 0; j < 4; ++j) {
                    const int n = n0 + wc * 64 + j * 16 + (lane & 15);
                    Cb[(size_t)b * c_rows * ncols + (size_t)m * ncols + n] =
                        (bf16)(acc[i][j][r] + bv);
                }
            }
        }
    } else {
        float* ct = (float*)smem;
        float* Cp = Cf + (size_t)b * c_rows * ncols;
        #pragma unroll
        for (int p = 0; p < 2; ++p) {
            if (wc == p) {
                #pragma unroll
                for (int i = 0; i < 4; ++i) {
                    const int ml = wr * 64 + i * 16 + (lane >> 4) * 4;
                    #pragma unroll
                    for (int r = 0; r < 4; ++r) {
                        const float bv = bias ? bias[b * bias_bstride + m0 + ml + r] : 0.f;
                        #pragma unroll
                        for (int j = 0; j < 4; ++j) {
                            const int n = j * 16 + (lane & 15);
                            ct[(ml + r) * 64 + n] = acc[i][j][r] + bv;
                        }
                    }
                }
            }
            __syncthreads();
            #pragma unroll
            for (int ii = 0; ii < 8; ++ii) {
                const int c   = t + 256 * ii;
                const int row = c >> 4;
                const int seg = c & 15;
                const float4 v = *(const float4*)(ct + row * 64 + seg * 4);
                *(float4*)(Cp + (size_t)(m0 + row) * ncols + n0 + p * 64 + seg * 4) = v;
            }
            __syncthreads();
        }
    }
}

// ---------------------------------------------------------------------------
extern "C" void kernel_launch(void* const* d_in, const int* in_sizes, int n_in,
                              void* d_out, int out_size, void* d_ws, size_t ws_size,
                              hipStream_t stream)
{
    (void)in_sizes; (void)n_in; (void)out_size;
    const float* x      = (const float*)d_in[0];
    const float* qkv_w  = (const float*)d_in[1];
    const float* qkv_b  = (const float*)d_in[2];
    const float* proj_w = (const float*)d_in[3];
    const float* proj_b = (const float*)d_in[4];

    float* out       = (float*)d_out;
    float* attn_mean = out + (size_t)BATCH * CH * NPIX;

    const size_t xt_bytes   = (size_t)BATCH * NPIX * CH * 2;            //  32 MiB
    const size_t part_bytes = (size_t)BATCH * HEADS * NSPLIT * HDIM * HDIM * 4; // 32 MiB
    const size_t wq_bytes   = (size_t)OC3 * KDEPTH * 2;                 // 1.5 MiB
    const size_t attn_bytes = (size_t)BATCH * HEADS * HDIM * HDIM * 4;  //   1 MiB
    const size_t wp_bytes   = (size_t)BATCH * CH * CH * 2;              //   4 MiB
    const size_t wpp_bytes  = (size_t)BATCH * CH * CH * 2;              //   4 MiB
    const size_t wvt_bytes  = (size_t)CH * CH * 2;                      // 0.5 MiB
    const size_t b2_bytes   = (size_t)BATCH * CH * 4;                   //  16 KiB
    const size_t need = xt_bytes + part_bytes + wq_bytes + attn_bytes +
                        wp_bytes + wpp_bytes + wvt_bytes + b2_bytes;
    if (ws_size < need) {
        fprintf(stderr, "[kernel_launch] ws_size=%zu < need=%zu — abort\n", ws_size, need);
        fflush(stderr);
        return;
    }

    char* p = (char*)d_ws;
    bf16*  xt     = (bf16*)p;             p += xt_bytes;
    float* part   = (float*)p;            p += part_bytes;
    bf16*  wq_b   = (bf16*)p;             p += wq_bytes;
    float* attn   = (float*)p;            p += attn_bytes;
    bf16*  wprime = (bf16*)p;             p += wp_bytes;
    bf16*  wpp    = (bf16*)p;             p += wpp_bytes;
    bf16*  wvt    = (bf16*)p;             p += wvt_bytes;
    float* bias2  = (float*)p;

    // 0) weight convert + Wv^T (merged)
    convert_wvt_kernel<<<dim3((OC3 * KDEPTH) / 256 + 64), 256, 0, stream>>>(
        qkv_w, wq_b, wvt);

    // 1) x -> xt (transpose + bf16)
    transpose_convert_kernel<<<dim3(NPIX / 64, CH / 64, BATCH), 256, 0, stream>>>(x, xt);

    // 2) Fused Q/K GEMM + QK^T partial -> part (qk never materialized)
    gemm_qks_kernel<<<dim3(NPIX / 128, HEADS, BATCH), 256, 0, stream>>>(
        wq_b, xt, qkv_b, part);

    // 3) reduce partials + softmax -> attn
    qk_reduce_softmax_kernel<<<dim3(8, BATCH * HEADS), 256, 0, stream>>>(part, attn);

    // 4) attn mean over heads (output 1)
    attn_mean_kernel<<<dim3(BATCH * HDIM * HDIM / 256), 256, 0, stream>>>(attn, attn_mean);

    // 5) W' = proj_w · blockdiag(attn)
    wprime_kernel<<<dim3(CH / 64, HEADS, BATCH), 256, 0, stream>>>(proj_w, attn, wprime);

    // 6) W'' = W' · Wv (bf16) ; bias'' = W'·bv + pb
    gemm128_kernel<<<dim3(CH / 128, CH / 128, BATCH), 256, 0, stream>>>(
        wprime, wvt, nullptr, 0, nullptr, wpp, CH, CH, (size_t)CH * CH, 0);
    bias2_kernel<<<dim3(BATCH * CH / 256), 256, 0, stream>>>(
        wprime, qkv_b + 2 * CH, proj_b, bias2);

    // 7) out = W''_b · x + bias''  (fp32 coalesced epilogue)
    gemm128_kernel<<<dim3(NPIX / 128, CH / 128, BATCH), 256, 0, stream>>>(
        wpp, xt, bias2, CH, out, nullptr, NPIX, CH, (size_t)CH * CH,
        (size_t)NPIX * KDEPTH);
}